// Round 8
// baseline (200.977 us; speedup 1.0000x reference)
//
#include <hip/hip_runtime.h>

#define C_CH 16
#define Hdim 128
#define Wdim 128
#define HWdim 16384
#define CHW (C_CH * HWdim)                 // 262144 floats: one [C][H][W] slab
#define Bdim 2
#define PAIR_ELEMS (Bdim * CHW)            // 524288

// x canvas: border 6 (= 2*max PAD, fused kernel needs double halo)
#define XWP 140
#define XHP 140
#define XPL (XHP * XWP)                    // 19600 per pair-plane

typedef float v2f __attribute__((ext_vector_type(2)));
typedef _Float16 h2 __attribute__((ext_vector_type(2)));
typedef _Float16 f16x8 __attribute__((ext_vector_type(8)));
typedef float f32x4 __attribute__((ext_vector_type(4)));

__device__ __forceinline__ unsigned pack2(float a, float b) {
  h2 h = {(_Float16)a, (_Float16)b};
  return __builtin_bit_cast(unsigned, h);
}
__device__ __forceinline__ void gadd(float* p, float v) {
  __hip_atomic_fetch_add(p, v, __ATOMIC_RELAXED, __HIP_MEMORY_SCOPE_AGENT);
}

// ---------------------------------------------------------------------------
// Prep layouts (MFMA A-operands read straight from global; hi+lo f16 split)
// bg simA  chunk/uvp = 8192B: [s2][mt4][row16][k32]      scaled
// bg readA chunk/2uv = 8192B: [l2][ck2][s2][c16][k32]    unscaled (flipped)
// tg simA  chunk/uvp = 2048B: [s2][row16(m<8)][k32]      scaled
// tg readA chunk/4uv = 2048B: [s2][c16][k32] k=q*8+m     unscaled (flipped)
// Per-lane fragment: + col*64 + g*16 bytes (plain, no swizzle).
// ---------------------------------------------------------------------------
struct PrepDesc {
  const float* mem;
  const float* temp;
  _Float16* simA;
  _Float16* readA;
  int M, D, P, tg;
};
struct PrepArgs { PrepDesc d[6]; };

// merged prep + padx: blocks [0,2048) build the x canvas, [2048,3224) prep A
__global__ __launch_bounds__(256) void k_preppad(PrepArgs a,
                                                 const float* __restrict__ bg,
                                                 const float* __restrict__ tg,
                                                 unsigned* __restrict__ xpad2)
{
  int bid = blockIdx.x;
  if (bid < 2048) {
    int idx = bid * 256 + threadIdx.x;          // 32 pair-planes * HW
    int pp = idx >> 14;
    int hw = idx & (HWdim - 1);
    int y = hw >> 7, x = hw & 127;
    int z = pp >> 3, cp = pp & 7;
    const float* src = (z < 2) ? bg : tg;
    int b = z & 1;
    float av = src[((b * C_CH + 2 * cp) << 14) + hw];
    float bv = src[((b * C_CH + 2 * cp + 1) << 14) + hw];
    xpad2[(size_t)pp * XPL + (y + 6) * XWP + (x + 6)] = pack2(av, bv);
    return;
  }
  int p = bid - 2048;                           // 0..1175 = (196 x, 6 y)
  int gy = p / 196, gx = p - gy * 196;
  PrepDesc de = a.d[gy];
  int n = de.M * de.D;
  int idx = gx * 256 + threadIdx.x;
  if (idx >= n) return;
  int m = idx / de.D;
  int d = idx - m * de.D;
  float val = de.mem[idx];
  float sc = de.temp[0] / sqrtf((float)de.D);
  int pp = de.P * de.P;
  int c = d / pp;
  int r = d - c * pp;
  int i = r / de.P;
  int j = r - i * de.P;
  int uv = i * de.P + j;                 // unflipped (sim correlation)
  int uvp = uv >> 1, luv = uv & 1;
  int kk = luv * 16 + c;
  int u = de.P - 1 - i, v = de.P - 1 - j;
  int uvf = u * de.P + v;                // flipped (read fold)
  float sv = val * sc;
  if (!de.tg) {
    int mt = m >> 4, row = m & 15;
    _Float16 hi = (_Float16)sv;
    size_t bi = (size_t)uvp * 4096 + mt * 512 + row * 32 + kk;
    de.simA[bi] = hi;                                   // s=0
    de.simA[bi + 2048] = (_Float16)(sv - (float)hi);    // s=1
    int ck = m >> 5, m5 = m & 31;
    _Float16 hr = (_Float16)val;
    size_t b2 = (size_t)uvf * 2048 + ck * 1024 + c * 32 + m5;
    de.readA[b2] = hr;                                  // s=0
    de.readA[b2 + 512] = (_Float16)(val - (float)hr);   // s=1
  } else {
    _Float16 hi = (_Float16)sv;          // m in 0..7, rows 8..15 stay zero
    size_t bi = (size_t)uvp * 1024 + m * 32 + kk;
    de.simA[bi] = hi;
    de.simA[bi + 512] = (_Float16)(sv - (float)hi);
    int ch = uvf >> 2, q = uvf & 3;
    _Float16 hr = (_Float16)val;
    size_t b2 = (size_t)ch * 1024 + c * 32 + q * 8 + (m & 7);
    de.readA[b2] = hr;
    de.readA[b2 + 512] = (_Float16)(val - (float)hr);
  }
}

// ---------------------------------------------------------------------------
// Fully fused sim + softmax + read (+ pooled partial) for bg AND tg.
// Block = 16x8 out px, 256 thr = 4 waves. A-operands from GLOBAL (L2) with
// hi/lo-staggered prefetch; B (x / att) in LDS. Only 4 barriers per block.
// LDS 41472 B (3 blocks/CU at VGPR<=170):
//   [0,17920)  x-halo [h][pix][16B]  (sim)   | [0,40960) att (read, aliases)
//   [40960,41472) pooled scratch
// Sim: wave w owns pixel-tiles w,w+4,..,w+16. Read: wave w owns rows 2w,2w+1.
// z: 0..5 bg (si*2+b), 6..11 tg. si 0..2 = {P7,P5,P3}.
// NOTE: do NOT raise min-waves (r6: (512,6) forced VGPR=40 -> 124MB spill).
// ---------------------------------------------------------------------------
struct FusedArgs {
  const unsigned* xpad2;
  const _Float16* simA[3];
  const _Float16* readA[3];
  const _Float16* simAtg[3];
  const _Float16* readAtg[3];
  float* fbgs[3];
  float* ftgs[3];
  float* pooled;
};

#define PSCR_OFF 40960
#define FX_SMEM 41472

template<int P, bool BG>
__device__ __forceinline__ void fused_body(
    const unsigned* __restrict__ xp,          // + plane base
    const _Float16* __restrict__ simA,
    const _Float16* __restrict__ readA,
    float* __restrict__ fout,                 // + b*CHW
    float* __restrict__ poolp,                // pooled + branch/b base
    unsigned char* smem, int tid, int x0, int y0)
{
  constexpr int PAD = P / 2;
  constexpr int THY = 8 + 2 * PAD, THX = 16 + 2 * PAD;  // att halo
  constexpr int XH = 8 + 4 * PAD, XW = 16 + 4 * PAD;    // x halo
  constexpr int NXP = XH * XW, NHP = THY * THX;
  constexpr int NT = (NHP + 15) / 16;
  constexpr int NUVP = (P * P + 1) / 2;
  constexpr int NCH = BG ? (P * P + 1) / 2 : (P * P + 3) / 4;
  constexpr int NMT = BG ? 4 : 1;
  constexpr int SCHUNK = NMT * 2 * 1024;     // sim A chunk bytes
  constexpr int RCHUNK = BG ? 8192 : 2048;   // read A chunk bytes
  constexpr int NTI = 5;

  unsigned char* xbuf = smem;                // sim phase
  unsigned char* att  = smem;                // read phase (aliases xbuf)
  float* pscr = (float*)(smem + PSCR_OFF);

  const int w = __builtin_amdgcn_readfirstlane(tid >> 6);
  const int lane = tid & 63;
  const int col = lane & 15, g = lane >> 4;
  const int alo = col * 64 + g * 16;         // per-lane A fragment offset

  // ---- stage x halo as [h][pix][16B] (c = h*8..h*8+7), b128 writes ----
  const int oy = y0 - 2 * PAD + 6, ox = x0 - 2 * PAD + 6;
  for (int t = tid; t < 2 * NXP; t += 256) {
    int h = (t >= NXP) ? 1 : 0;
    int pix = t - h * NXP;
    int ly = pix / XW, lx = pix - ly * XW;
    const unsigned* s = xp + (size_t)(h * 4) * XPL + (oy + ly) * XWP + (ox + lx);
    uint4 vv = { s[0], s[XPL], s[2 * XPL], s[3 * XPL] };
    *(uint4*)(xbuf + (h * NXP + pix) * 16) = vv;
  }

  // ---- per-tile pixel coords (wave w: tiles w, w+4, ..., w+16) ----
  int ayv[NTI], axv[NTI];
#pragma unroll
  for (int ti = 0; ti < NTI; ++ti) {
    int nt = w + ti * 4;
    int pix = nt * 16 + col;
    if (pix > NHP - 1) pix = NHP - 1;
    ayv[ti] = pix / THX;
    axv[ti] = pix - ayv[ti] * THX;
  }

  f32x4 acc[NTI][NMT];
#pragma unroll
  for (int ti = 0; ti < NTI; ++ti)
#pragma unroll
    for (int mt = 0; mt < NMT; ++mt) acc[ti][mt] = (f32x4){0.f, 0.f, 0.f, 0.f};

  const unsigned char* sA = (const unsigned char*)simA;
  f16x8 ah[NMT], al[NMT];
#pragma unroll
  for (int mt = 0; mt < NMT; ++mt)
    ah[mt] = *(const f16x8*)(sA + mt * 1024 + alo);

  __syncthreads();                           // (1) x halo staged

  // ---- sim K-loop: A from global, hi/lo staggered; no barriers ----
  for (int uvp = 0; uvp < NUVP; ++uvp) {
    const unsigned char* cb = sA + (size_t)uvp * SCHUNK;
#pragma unroll
    for (int mt = 0; mt < NMT; ++mt)
      al[mt] = *(const f16x8*)(cb + (NMT + mt) * 1024 + alo);

    int uva = 2 * uvp;
    int uvb = uva + 1; if (uvb >= P * P) uvb = uva;   // pad slot: zero A
    const int ua = uva / P, va = uva - ua * P;
    const int ub = uvb / P, vb = uvb - ub * P;
    const int u_ = (g >= 2) ? ub : ua;
    const int v_ = (g >= 2) ? vb : va;

    f16x8 bbv[NTI];
#pragma unroll
    for (int ti = 0; ti < NTI; ++ti) {
      if (w + ti * 4 < NT) {
        int xpix = (ayv[ti] + u_) * XW + axv[ti] + v_;
        bbv[ti] = *(const f16x8*)(xbuf + ((g & 1) * NXP + xpix) * 16);
#pragma unroll
        for (int mt = 0; mt < NMT; ++mt)
          acc[ti][mt] = __builtin_amdgcn_mfma_f32_16x16x32_f16(ah[mt], bbv[ti], acc[ti][mt], 0, 0, 0);
      }
    }
    if (uvp + 1 < NUVP) {
#pragma unroll
      for (int mt = 0; mt < NMT; ++mt)
        ah[mt] = *(const f16x8*)(cb + SCHUNK + mt * 1024 + alo);
    }
#pragma unroll
    for (int ti = 0; ti < NTI; ++ti) {
      if (w + ti * 4 < NT) {
#pragma unroll
        for (int mt = 0; mt < NMT; ++mt)
          acc[ti][mt] = __builtin_amdgcn_mfma_f32_16x16x32_f16(al[mt], bbv[ti], acc[ti][mt], 0, 0, 0);
      }
    }
  }

  __syncthreads();                           // (2) all xbuf reads done

  // ---- softmax + att store to LDS (att aliases xbuf region) ----
#pragma unroll
  for (int ti = 0; ti < NTI; ++ti) {
    int nt = w + ti * 4;
    if (nt < NT) {
      int pa = nt * 16 + col;
      int say = pa / THX, sax = pa - say * THX;
      int gy = y0 + say - PAD, gx = x0 + sax - PAD;
      bool inimg = (pa < NHP) & (gy >= 0) & (gy < Hdim) & (gx >= 0) & (gx < Wdim);
      if constexpr (BG) {
        float l[16];
#pragma unroll
        for (int mt = 0; mt < 4; ++mt)
#pragma unroll
          for (int r = 0; r < 4; ++r) l[mt * 4 + r] = acc[ti][mt][r];
        float mx = l[0];
#pragma unroll
        for (int i2 = 1; i2 < 16; ++i2) mx = fmaxf(mx, l[i2]);
        mx = fmaxf(mx, __shfl_xor(mx, 16));
        mx = fmaxf(mx, __shfl_xor(mx, 32));
        float sum = 0.f;
#pragma unroll
        for (int i2 = 0; i2 < 16; ++i2) { l[i2] = __expf(l[i2] - mx); sum += l[i2]; }
        sum += __shfl_xor(sum, 16);
        sum += __shfl_xor(sum, 32);
        float inv = inimg ? (1.f / sum) : 0.f;
        unsigned char* base = att + pa * 128;
        int swz = (pa & 7) << 4;
#pragma unroll
        for (int mt = 0; mt < 4; ++mt) {
          uint2 st = { pack2(l[mt * 4 + 0] * inv, l[mt * 4 + 1] * inv),
                       pack2(l[mt * 4 + 2] * inv, l[mt * 4 + 3] * inv) };
          *(uint2*)(base + ((mt * 32 + g * 8) ^ swz)) = st;
        }
      } else {
        float l0 = acc[ti][0][0], l1 = acc[ti][0][1];
        float l2 = acc[ti][0][2], l3 = acc[ti][0][3];
        float mx = fmaxf(fmaxf(l0, l1), fmaxf(l2, l3));
        mx = fmaxf(mx, __shfl_xor(mx, 16));      // g0<->g1 (m 0..7)
        l0 = __expf(l0 - mx); l1 = __expf(l1 - mx);
        l2 = __expf(l2 - mx); l3 = __expf(l3 - mx);
        float sum = l0 + l1 + l2 + l3;
        sum += __shfl_xor(sum, 16);
        float inv = inimg ? (1.f / sum) : 0.f;
        if (g < 2) {                              // m = g*4 + r
          uint2 st = { pack2(l0 * inv, l1 * inv), pack2(l2 * inv, l3 * inv) };
          *(uint2*)(att + pa * 16 + g * 8) = st;
        }
      }
    }
  }
  __syncthreads();                           // (3) att complete

  // ---- read phase: wave w owns rows 2w, 2w+1; A from global ----
  constexpr int NRC = BG ? 4 : 2;
  f32x4 racc[2][NRC];
#pragma unroll
  for (int r = 0; r < 2; ++r)
#pragma unroll
    for (int q = 0; q < NRC; ++q) racc[r][q] = (f32x4){0.f, 0.f, 0.f, 0.f};

  const unsigned char* rA = (const unsigned char*)readA;
  if constexpr (BG) {
    f16x8 rah[4];                            // (l,ck) for s=0
#pragma unroll
    for (int l = 0; l < 2; ++l)
#pragma unroll
      for (int ck = 0; ck < 2; ++ck)
        rah[l * 2 + ck] = *(const f16x8*)(rA + l * 4096 + ck * 2048 + alo);

    for (int ch = 0; ch < NCH; ++ch) {
      const unsigned char* cb = rA + (size_t)ch * RCHUNK;
      f16x8 ral[4];
#pragma unroll
      for (int l = 0; l < 2; ++l)
#pragma unroll
        for (int ck = 0; ck < 2; ++ck)
          ral[l * 2 + ck] = *(const f16x8*)(cb + l * 4096 + ck * 2048 + 1024 + alo);

      f16x8 bbv[2][2][2];                    // [l][row][ck]
#pragma unroll
      for (int l = 0; l < 2; ++l) {
        int uv = 2 * ch + l;
        if (uv > P * P - 1) uv = P * P - 1;  // pad slot: zero A
        int u = uv / P, v = uv - u * P;
#pragma unroll
        for (int r = 0; r < 2; ++r) {
          int pix = (2 * w + r + u) * THX + (col + v);
          int swz = (pix & 7) << 4;
#pragma unroll
          for (int ck = 0; ck < 2; ++ck)
            bbv[l][r][ck] = *(const f16x8*)(att + pix * 128 + ((ck * 64 + g * 16) ^ swz));
        }
      }
#pragma unroll
      for (int l = 0; l < 2; ++l)
#pragma unroll
        for (int r = 0; r < 2; ++r)
#pragma unroll
          for (int ck = 0; ck < 2; ++ck)
            racc[r][ck * 2 + 0] = __builtin_amdgcn_mfma_f32_16x16x32_f16(
                rah[l * 2 + ck], bbv[l][r][ck], racc[r][ck * 2 + 0], 0, 0, 0);
      if (ch + 1 < NCH) {
#pragma unroll
        for (int l = 0; l < 2; ++l)
#pragma unroll
          for (int ck = 0; ck < 2; ++ck)
            rah[l * 2 + ck] = *(const f16x8*)(cb + RCHUNK + l * 4096 + ck * 2048 + alo);
      }
#pragma unroll
      for (int l = 0; l < 2; ++l)
#pragma unroll
        for (int r = 0; r < 2; ++r)
#pragma unroll
          for (int ck = 0; ck < 2; ++ck)
            racc[r][ck * 2 + 1] = __builtin_amdgcn_mfma_f32_16x16x32_f16(
                ral[l * 2 + ck], bbv[l][r][ck], racc[r][ck * 2 + 1], 0, 0, 0);
    }
  } else {
    f16x8 tah = *(const f16x8*)(rA + alo);
    for (int ch = 0; ch < NCH; ++ch) {
      const unsigned char* cb = rA + (size_t)ch * RCHUNK;
      f16x8 tal = *(const f16x8*)(cb + 1024 + alo);
      int uv = 4 * ch + g;                   // lane's g = K-slot q
      if (uv > P * P - 1) uv = P * P - 1;    // pad: zero A rows
      int u = uv / P, v = uv - u * P;
      f16x8 bbt[2];
#pragma unroll
      for (int r = 0; r < 2; ++r) {
        int pix = (2 * w + r + u) * THX + (col + v);
        bbt[r] = *(const f16x8*)(att + pix * 16);
      }
#pragma unroll
      for (int r = 0; r < 2; ++r)
        racc[r][0] = __builtin_amdgcn_mfma_f32_16x16x32_f16(tah, bbt[r], racc[r][0], 0, 0, 0);
      if (ch + 1 < NCH) tah = *(const f16x8*)(cb + RCHUNK + alo);
#pragma unroll
      for (int r = 0; r < 2; ++r)
        racc[r][1] = __builtin_amdgcn_mfma_f32_16x16x32_f16(tal, bbt[r], racc[r][1], 0, 0, 0);
    }
  }

  // ---- epilogue: divisor + store + pooled partial (shfl tree) ----
#pragma unroll
  for (int r = 0; r < 2; ++r) {
    f32x4 sv;
    if constexpr (BG) sv = (racc[r][0] + racc[r][1]) + (racc[r][2] + racc[r][3]);
    else              sv = racc[r][0] + racc[r][1];
    int gy = y0 + 2 * w + r, gx = x0 + col;
    int cy = min(P - 1, gy + PAD) - max(0, gy + PAD - (Hdim - 1)) + 1;
    int cx = min(P - 1, gx + PAD) - max(0, gx + PAD - (Wdim - 1)) + 1;
    float inv = 1.f / ((float)(cy * cx) + 1e-8f);
    float o0 = sv[0] * inv, o1 = sv[1] * inv, o2 = sv[2] * inv, o3 = sv[3] * inv;
    float* outp = fout + (size_t)(g * 4) * HWdim + gy * Wdim + gx;
    outp[0] = o0;
    outp[(size_t)1 * HWdim] = o1;
    outp[(size_t)2 * HWdim] = o2;
    outp[(size_t)3 * HWdim] = o3;

    float s0 = o0, s1 = o1, s2 = o2, s3 = o3;
#pragma unroll
    for (int mask = 1; mask < 16; mask <<= 1) {
      s0 += __shfl_xor(s0, mask);
      s1 += __shfl_xor(s1, mask);
      s2 += __shfl_xor(s2, mask);
      s3 += __shfl_xor(s3, mask);
    }
    if (col == 0) {
      float* rp = pscr + ((2 * w + r) * 4 + g) * 4;
      rp[0] = s0; rp[1] = s1; rp[2] = s2; rp[3] = s3;
    }
  }
  __syncthreads();                           // (4) pool scratch ready
  if (tid < 16) {                            // c = tid = g*4+r
    float t = 0.f;
#pragma unroll
    for (int ww = 0; ww < 8; ++ww) t += pscr[ww * 16 + tid];
    gadd(poolp + tid, t * (1.0f / (float)HWdim));
  }
}

__global__ __launch_bounds__(256, 3) void k_fused(FusedArgs a) {
  __shared__ __align__(16) unsigned char smem[FX_SMEM];
  const int z = blockIdx.z;
  const int x0 = blockIdx.x * 16, y0 = blockIdx.y * 8;
  const int tid = threadIdx.x;
  if (z < 6) {
    const int si = z >> 1, b = z & 1;
    const unsigned* xp = a.xpad2 + (size_t)(b * 8) * XPL;
    float* pp = a.pooled + b * 16;
    if (si == 0)
      fused_body<7, true>(xp, a.simA[0], a.readA[0], a.fbgs[0] + (size_t)b * CHW, pp, smem, tid, x0, y0);
    else if (si == 1)
      fused_body<5, true>(xp, a.simA[1], a.readA[1], a.fbgs[1] + (size_t)b * CHW, pp, smem, tid, x0, y0);
    else
      fused_body<3, true>(xp, a.simA[2], a.readA[2], a.fbgs[2] + (size_t)b * CHW, pp, smem, tid, x0, y0);
  } else {
    const int zz = z - 6, si = zz >> 1, b = zz & 1;
    const unsigned* xp = a.xpad2 + (size_t)((2 + b) * 8) * XPL;
    float* pp = a.pooled + 32 + b * 16;
    if (si == 0)
      fused_body<7, false>(xp, a.simAtg[0], a.readAtg[0], a.ftgs[0] + (size_t)b * CHW, pp, smem, tid, x0, y0);
    else if (si == 1)
      fused_body<5, false>(xp, a.simAtg[1], a.readAtg[1], a.ftgs[1] + (size_t)b * CHW, pp, smem, tid, x0, y0);
    else
      fused_body<3, false>(xp, a.simAtg[2], a.readAtg[2], a.ftgs[2] + (size_t)b * CHW, pp, smem, tid, x0, y0);
  }
}

// ---------------------------------------------------------------------------
// Output blend with inlined fusion MLP (per-block recompute from pooled).
// 1024 blocks x 256 thr; each thread handles one float4 quad.
// ---------------------------------------------------------------------------
__global__ __launch_bounds__(256) void k_out(
    const float* __restrict__ fbg, const float* __restrict__ ftg,
    const float* __restrict__ pooled,
    const float* __restrict__ w1b, const float* __restrict__ b1b,
    const float* __restrict__ w2b, const float* __restrict__ b2b,
    const float* __restrict__ w1t, const float* __restrict__ b1t,
    const float* __restrict__ w2t, const float* __restrict__ b2t,
    float* __restrict__ out)
{
  __shared__ float hdn[2][2][4];
  __shared__ float lgs[2][2][48];
  __shared__ float swt[12][16];
  const int t = threadIdx.x;
  if (t < 16) {                 // br=t>>3, b=(t>>2)&1, h=t&3
    int br = t >> 3, b = (t >> 2) & 1, h = t & 3;
    const float* w1 = br ? w1t : w1b;
    const float* b1 = br ? b1t : b1b;
    float s = b1[h];
    for (int c = 0; c < C_CH; ++c) s += pooled[br * 32 + b * 16 + c] * w1[h * 16 + c];
    hdn[br][b][h] = fmaxf(s, 0.f);
  }
  __syncthreads();
  if (t < 192) {                // br=t/96, b, j
    int br = t / 96, r = t - br * 96, b = r / 48, j = r - b * 48;
    const float* w2 = br ? w2t : w2b;
    const float* b2 = br ? b2t : b2b;
    float s = b2[j];
    for (int h = 0; h < 4; ++h) s += hdn[br][b][h] * w2[j * 4 + h];
    lgs[br][b][j] = s;
  }
  __syncthreads();
  if (t < 64) {                 // br=t>>5, b=(t>>4)&1, c=t&15
    int br = t >> 5, b = (t >> 4) & 1, c = t & 15;
    float l0 = lgs[br][b][c], l1 = lgs[br][b][16 + c], l2 = lgs[br][b][32 + c];
    float m = fmaxf(l0, fmaxf(l1, l2));
    float e0 = __expf(l0 - m), e1 = __expf(l1 - m), e2 = __expf(l2 - m);
    float inv = 1.f / (e0 + e1 + e2);
    swt[(br * 2 + b) * 3 + 0][c] = e0 * inv;
    swt[(br * 2 + b) * 3 + 1][c] = e1 * inv;
    swt[(br * 2 + b) * 3 + 2][c] = e2 * inv;
  }
  __syncthreads();

  int base = (blockIdx.x * 256 + t) * 4;         // quad base, 0..2^20
  int br  = base >> 19;
  int rem = base & ((1 << 19) - 1);
  int b   = rem >> 18;
  int off = rem & ((1 << 18) - 1);
  int c   = off >> 14;
  const float* f = (br == 0) ? fbg : ftg;
  int wb = (br * 2 + b) * 3;
  f32x4 acc = {0.f, 0.f, 0.f, 0.f};
#pragma unroll
  for (int s = 0; s < 3; ++s) {
    f32x4 v = *(const f32x4*)(f + (size_t)(s * 2 + b) * CHW + off);
    float wv = swt[wb + s][c];
    acc = __builtin_elementwise_fma((f32x4){wv, wv, wv, wv}, v, acc);
  }
  *(f32x4*)(out + base) = acc;
}

// ---------------------------------------------------------------------------
extern "C" void kernel_launch(void* const* d_in, const int* in_sizes, int n_in,
                              void* d_out, int out_size, void* d_ws, size_t ws_size,
                              hipStream_t stream)
{
  const float* bg = (const float*)d_in[0];
  const float* tg = (const float*)d_in[1];
  const float* bg_mem[3]  = {(const float*)d_in[2],  (const float*)d_in[6],  (const float*)d_in[10]};
  const float* tg_mem[3]  = {(const float*)d_in[3],  (const float*)d_in[7],  (const float*)d_in[11]};
  const float* bg_temp[3] = {(const float*)d_in[4],  (const float*)d_in[8],  (const float*)d_in[12]};
  const float* tg_temp[3] = {(const float*)d_in[5],  (const float*)d_in[9],  (const float*)d_in[13]};
  const float* bg_fc1_w = (const float*)d_in[14];
  const float* bg_fc1_b = (const float*)d_in[15];
  const float* bg_fc2_w = (const float*)d_in[16];
  const float* bg_fc2_b = (const float*)d_in[17];
  const float* tg_fc1_w = (const float*)d_in[18];
  const float* tg_fc1_b = (const float*)d_in[19];
  const float* tg_fc2_w = (const float*)d_in[20];
  const float* tg_fc2_b = (const float*)d_in[21];

  unsigned* ws = (unsigned*)d_ws;
  unsigned* xpad2   = ws;                                    // 627,200 u32
  float*    pooled  = (float*)(ws + (size_t)32 * XPL);       // 64
  float*    wt      = pooled + 64;                           // 192 (unused pad)
  _Float16* simA    = (_Float16*)(wt + 192);                 // 176,128 halfs
  _Float16* readA   = simA + 176128;                         // 176,128 halfs
  _Float16* simAtg  = readA + 176128;                        // 44,032 halfs
  _Float16* readAtg = simAtg + 44032;                        // 23,552 halfs
  float*    ftg     = (float*)(readAtg + 23552);             // 6*CHW
  float*    fbg     = ftg + (size_t)6 * CHW;                 // 6*CHW

  // zero xpad2 border + pooled + all A arrays (pad slots) in one shot
  hipMemsetAsync(xpad2, 0, (size_t)837376 * 4, stream);

  const int   Ms[6] = {64, 64, 64, 8, 8, 8};
  const int   Ps[6] = {3, 5, 7, 3, 5, 7};
  const float* mems[6]  = {bg_mem[0], bg_mem[1], bg_mem[2], tg_mem[0], tg_mem[1], tg_mem[2]};
  const float* temps[6] = {bg_temp[0], bg_temp[1], bg_temp[2], tg_temp[0], tg_temp[1], tg_temp[2]};

  // per-scale offsets (halfs), si 0..2 = P7,P5,P3
  const size_t aOff[3]   = {0, 102400, 155648};   // bg sim & read (same sizes)
  const size_t sOffTg[3] = {0, 25600, 38912};     // tg sim
  const size_t rOffTg[3] = {0, 13312, 20480};     // tg read

  PrepArgs pa;
  for (int k = 0; k < 6; ++k) {
    int D = C_CH * Ps[k] * Ps[k];
    int si = 2 - (k % 3);                         // PS index -> scale index
    if (k < 3)
      pa.d[k] = {mems[k], temps[k], simA + aOff[si], readA + aOff[si],
                 Ms[k], D, Ps[k], 0};
    else
      pa.d[k] = {mems[k], temps[k], simAtg + sOffTg[si], readAtg + rOffTg[si],
                 Ms[k], D, Ps[k], 1};
  }
  k_preppad<<<3224, 256, 0, stream>>>(pa, bg, tg, xpad2);

  FusedArgs fa;
  fa.xpad2 = xpad2;
  fa.pooled = pooled;
  for (int si = 0; si < 3; ++si) {
    int p = 2 - si;
    fa.simA[si]    = simA + aOff[si];
    fa.readA[si]   = readA + aOff[si];
    fa.simAtg[si]  = simAtg + sOffTg[si];
    fa.readAtg[si] = readAtg + rOffTg[si];
    fa.fbgs[si]    = fbg + (size_t)p * 2 * CHW;
    fa.ftgs[si]    = ftg + (size_t)p * 2 * CHW;
  }

  k_fused<<<dim3(8, 16, 12), 256, 0, stream>>>(fa);

  k_out<<<1024, 256, 0, stream>>>(fbg, ftg, pooled,
                                  bg_fc1_w, bg_fc1_b, bg_fc2_w, bg_fc2_b,
                                  tg_fc1_w, tg_fc1_b, tg_fc2_w, tg_fc2_b,
                                  (float*)d_out);
}

// Round 9
// 160.928 us; speedup vs baseline: 1.2489x; 1.2489x over previous
//
#include <hip/hip_runtime.h>

#define C_CH 16
#define Hdim 128
#define Wdim 128
#define HWdim 16384
#define CHW (C_CH * HWdim)                 // 262144 floats: one [C][H][W] slab
#define Bdim 2
#define PAIR_ELEMS (Bdim * CHW)            // 524288

// x canvas: border 6 (= 2*max PAD, fused kernel needs double halo)
#define XWP 140
#define XHP 140
#define XPL (XHP * XWP)                    // 19600 per pair-plane

typedef float v2f __attribute__((ext_vector_type(2)));
typedef _Float16 h2 __attribute__((ext_vector_type(2)));
typedef _Float16 f16x8 __attribute__((ext_vector_type(8)));
typedef float f32x4 __attribute__((ext_vector_type(4)));

__device__ __forceinline__ unsigned pack2(float a, float b) {
  h2 h = {(_Float16)a, (_Float16)b};
  return __builtin_bit_cast(unsigned, h);
}
__device__ __forceinline__ void gadd(float* p, float v) {
  __hip_atomic_fetch_add(p, v, __ATOMIC_RELAXED, __HIP_MEMORY_SCOPE_AGENT);
}

// ---------------------------------------------------------------------------
// Prep layouts (MFMA A-operands, hi+lo f16 split, r7 LDS-swizzled form)
// bg simA  [uvp][s(2)][mt(4)][row16][k32 swz]   scaled   (chunk 8KB)
// bg readA [uvf][ck(2)][s(2)][c16][k32 swz]     unscaled (flipped, chunk 8KB)
// tg simA  [uvp][s(2)][row16(m<8)][k32 swz]     scaled   (chunk 2KB)
// tg readA [ch][s(2)][c16][k32 swz] k=q*8+m     unscaled (flipped, chunk 2KB)
// k-swizzle: halfs offset (kg ^ (row&3))*8 + kl  -> conflict-free A reads
// ---------------------------------------------------------------------------
struct PrepDesc {
  const float* mem;
  const float* temp;
  _Float16* simA;
  _Float16* readA;
  int M, D, P, tg;
};
struct PrepArgs { PrepDesc d[6]; };

// merged prep + padx: blocks [0,2048) build the x canvas, [2048,3224) prep A
__global__ __launch_bounds__(256) void k_preppad(PrepArgs a,
                                                 const float* __restrict__ bg,
                                                 const float* __restrict__ tg,
                                                 unsigned* __restrict__ xpad2)
{
  int bid = blockIdx.x;
  if (bid < 2048) {
    int idx = bid * 256 + threadIdx.x;          // 32 pair-planes * HW
    int pp = idx >> 14;
    int hw = idx & (HWdim - 1);
    int y = hw >> 7, x = hw & 127;
    int z = pp >> 3, cp = pp & 7;
    const float* src = (z < 2) ? bg : tg;
    int b = z & 1;
    float av = src[((b * C_CH + 2 * cp) << 14) + hw];
    float bv = src[((b * C_CH + 2 * cp + 1) << 14) + hw];
    xpad2[(size_t)pp * XPL + (y + 6) * XWP + (x + 6)] = pack2(av, bv);
    return;
  }
  int p = bid - 2048;                           // 0..1175 = (196 x, 6 y)
  int gy = p / 196, gx = p - gy * 196;
  PrepDesc de = a.d[gy];
  int n = de.M * de.D;
  int idx = gx * 256 + threadIdx.x;
  if (idx >= n) return;
  int m = idx / de.D;
  int d = idx - m * de.D;
  float val = de.mem[idx];
  float sc = de.temp[0] / sqrtf((float)de.D);
  int pp = de.P * de.P;
  int c = d / pp;
  int r = d - c * pp;
  int i = r / de.P;
  int j = r - i * de.P;
  int uv = i * de.P + j;                 // unflipped (sim correlation)
  int uvp = uv >> 1, luv = uv & 1;
  int kk = luv * 16 + c, kg = kk >> 3, kl = kk & 7;
  int u = de.P - 1 - i, v = de.P - 1 - j;
  int uvf = u * de.P + v;                // flipped (read fold)
  float sv = val * sc;
  if (!de.tg) {
    int mt = m >> 4, row = m & 15;
    _Float16 hi = (_Float16)sv;
    size_t bi = ((size_t)uvp * 8 + mt) * 512 + row * 32 +
                (size_t)((kg ^ (row & 3)) * 8 + kl);
    de.simA[bi] = hi;
    de.simA[bi + 2048] = (_Float16)(sv - (float)hi);
    int ck = m >> 5, m5 = m & 31, kg2 = m5 >> 3, kl2 = m5 & 7;
    _Float16 hr = (_Float16)val;
    size_t b2 = (size_t)uvf * 2048 + (size_t)(ck * 2) * 512 + c * 32 +
                (size_t)((kg2 ^ (c & 3)) * 8 + kl2);
    de.readA[b2] = hr;
    de.readA[b2 + 512] = (_Float16)(val - (float)hr);
  } else {
    _Float16 hi = (_Float16)sv;          // m in 0..7, rows 8..15 stay zero
    size_t bi = (size_t)(uvp * 2) * 512 + m * 32 +
                (size_t)((kg ^ (m & 3)) * 8 + kl);
    de.simA[bi] = hi;
    de.simA[bi + 512] = (_Float16)(sv - (float)hi);
    int ch = uvf >> 2, q = uvf & 3;
    _Float16 hr = (_Float16)val;
    size_t b2 = (size_t)ch * 1024 + c * 32 +
                (size_t)((q ^ (c & 3)) * 8 + (m & 7));
    de.readA[b2] = hr;
    de.readA[b2 + 512] = (_Float16)(val - (float)hr);
  }
}

// ---------------------------------------------------------------------------
// Fully fused sim + softmax + read (+ pooled partial) for bg AND tg.
// Block = 16x16 out px (r9: doubled from 16x8 for 2x A-reuse), 512 thr.
// LDS 72704 B, 2 blocks/CU:
//   [0,25088)      x-halo [h][pix][16B]          (sim phase)
//   [25088,41472)  sim A double buffer           (under att; dead by softmax)
//   [0,63488)      att (bg 128B/px swz, tg 16B)  (read phase; aliases both)
//   [63488,71680)  read A single buffer 8KB
//   [71680,72704)  pooled scratch
// Sim: 1 barrier/chunk; wave w owns N-tiles w, w+8, w+16, w+24.
// Read: 2 barriers/chunk; wave w owns out rows 2w, 2w+1.
// z: 0..5 bg (si*2+b), 6..11 tg. si 0..2 = {P7,P5,P3}.
// NOTE: (512,4) VGPR cap 128 — do NOT raise min-waves (r6: (512,6) -> spill);
// do NOT move A to global (r8: latency-bound, 107us).
// ---------------------------------------------------------------------------
struct FusedArgs {
  const unsigned* xpad2;
  const _Float16* simA[3];
  const _Float16* readA[3];
  const _Float16* simAtg[3];
  const _Float16* readAtg[3];
  float* fbgs[3];
  float* ftgs[3];
  float* pooled;
};

#define SDB_OFF 25088
#define RBUF_OFF 63488
#define PSCR_OFF 71680
#define FX_SMEM 72704

template<int P, bool BG>
__device__ __forceinline__ void fused_body(
    const unsigned* __restrict__ xp,          // + plane base
    const _Float16* __restrict__ simA,
    const _Float16* __restrict__ readA,
    float* __restrict__ fout,                 // + b*CHW
    float* __restrict__ poolp,                // pooled + branch/b base
    unsigned char* smem, int tid, int x0, int y0)
{
  constexpr int PAD = P / 2;
  constexpr int THY = 16 + 2 * PAD, THX = 16 + 2 * PAD;  // att halo
  constexpr int XH = 16 + 4 * PAD, XW = 16 + 4 * PAD;    // x halo
  constexpr int NXP = XH * XW, NHP = THY * THX;
  constexpr int NT = (NHP + 15) / 16;
  constexpr int NUVP = (P * P + 1) / 2;
  constexpr int NCH = BG ? (P * P + 1) / 2 : (P * P + 3) / 4;
  constexpr int NMT = BG ? 4 : 1;
  constexpr int SCHB = BG ? 8192 : 2048;     // sim A chunk bytes
  constexpr int RCHB = BG ? 8192 : 2048;     // read A chunk bytes
  constexpr int SLD = SCHB / 16, RLD = RCHB / 16;
  constexpr int NRACC = BG ? 4 : 2;
  constexpr int NTI = 4;                     // sim N-tiles per wave

  unsigned char* xbuf = smem;                // sim phase
  unsigned char* att  = smem;                // read phase (aliases xbuf+sdb)
  unsigned char* sdb  = smem + SDB_OFF;      // sim A dbuf
  unsigned char* rbuf = smem + RBUF_OFF;     // read A single buf
  float* pscr = (float*)(smem + PSCR_OFF);

  const int w = __builtin_amdgcn_readfirstlane(tid >> 6);
  const int lane = tid & 63;
  const int col = lane & 15, g = lane >> 4;

  // ---- stage x halo as [h][pix][16B] (c = h*8..h*8+7), b128 writes ----
  const int oy = y0 - 2 * PAD + 6, ox = x0 - 2 * PAD + 6;
  for (int t = tid; t < 2 * NXP; t += 512) {
    int h = (t >= NXP) ? 1 : 0;
    int pix = t - h * NXP;
    int ly = pix / XW, lx = pix - ly * XW;
    const unsigned* s = xp + (size_t)(h * 4) * XPL + (oy + ly) * XWP + (ox + lx);
    uint4 vv = { s[0], s[XPL], s[2 * XPL], s[3 * XPL] };
    *(uint4*)(xbuf + (h * NXP + pix) * 16) = vv;
  }

  // ---- per-tile pixel coords (wave w: tiles w, w+8, w+16, w+24) ----
  int ayv[NTI], axv[NTI];
#pragma unroll
  for (int ti = 0; ti < NTI; ++ti) {
    int nt = w + ti * 8;
    int pix = nt * 16 + col;
    if (pix > NHP - 1) pix = NHP - 1;
    ayv[ti] = pix / THX;
    axv[ti] = pix - ayv[ti] * THX;
  }

  f32x4 acc[NTI][NMT];
#pragma unroll
  for (int ti = 0; ti < NTI; ++ti)
#pragma unroll
    for (int mt = 0; mt < NMT; ++mt) acc[ti][mt] = (f32x4){0.f, 0.f, 0.f, 0.f};

  // ---- sim K-loop, double-buffered A, 1 barrier/chunk ----
  uint4 sreg;
  if (tid < SLD) sreg = *((const uint4*)simA + tid);
  for (int uvp = 0; uvp < NUVP; ++uvp) {
    if (tid < SLD) {
      *((uint4*)(sdb + (uvp & 1) * SCHB) + tid) = sreg;
      if (uvp + 1 < NUVP)
        sreg = *((const uint4*)(simA + (size_t)(uvp + 1) * (SCHB / 2)) + tid);
    }
    __syncthreads();

    const unsigned char* ab = sdb + (uvp & 1) * SCHB;
    f16x8 af[2][NMT];
#pragma unroll
    for (int s = 0; s < 2; ++s)
#pragma unroll
      for (int mt = 0; mt < NMT; ++mt)
        af[s][mt] = *(const f16x8*)(ab + (s * NMT + mt) * 1024 + col * 64 +
                                    ((g ^ (col & 3)) << 4));

    int uva = 2 * uvp;
    int uvb = uva + 1; if (uvb >= P * P) uvb = uva;   // pad slot: zero A
    const int ua = uva / P, va = uva - ua * P;
    const int ub = uvb / P, vb = uvb - ub * P;
    const int u_ = (g >= 2) ? ub : ua;
    const int v_ = (g >= 2) ? vb : va;

#pragma unroll
    for (int ti = 0; ti < NTI; ++ti) {
      int nt = w + ti * 8;
      if (nt < NT) {
        int xpix = (ayv[ti] + u_) * XW + axv[ti] + v_;
        f16x8 bb = *(const f16x8*)(xbuf + ((g & 1) * NXP + xpix) * 16);
#pragma unroll
        for (int mt = 0; mt < NMT; ++mt) {
          acc[ti][mt] = __builtin_amdgcn_mfma_f32_16x16x32_f16(af[0][mt], bb, acc[ti][mt], 0, 0, 0);
          acc[ti][mt] = __builtin_amdgcn_mfma_f32_16x16x32_f16(af[1][mt], bb, acc[ti][mt], 0, 0, 0);
        }
      }
    }
  }

  // prefetch first read-A chunk; fence xbuf/sdb reads before att overwrites
  uint4 rreg;
  if (tid < RLD) rreg = *((const uint4*)readA + tid);
  __syncthreads();

  // ---- softmax + att store to LDS (att aliases xbuf+sdb region) ----
#pragma unroll
  for (int ti = 0; ti < NTI; ++ti) {
    int nt = w + ti * 8;
    if (nt < NT) {
      int pa = nt * 16 + col;
      int say = pa / THX, sax = pa - say * THX;
      int gy = y0 + say - PAD, gx = x0 + sax - PAD;
      bool inimg = (pa < NHP) & (gy >= 0) & (gy < Hdim) & (gx >= 0) & (gx < Wdim);
      if constexpr (BG) {
        float l[16];
#pragma unroll
        for (int mt = 0; mt < 4; ++mt)
#pragma unroll
          for (int r = 0; r < 4; ++r) l[mt * 4 + r] = acc[ti][mt][r];
        float mx = l[0];
#pragma unroll
        for (int i2 = 1; i2 < 16; ++i2) mx = fmaxf(mx, l[i2]);
        mx = fmaxf(mx, __shfl_xor(mx, 16));
        mx = fmaxf(mx, __shfl_xor(mx, 32));
        float sum = 0.f;
#pragma unroll
        for (int i2 = 0; i2 < 16; ++i2) { l[i2] = __expf(l[i2] - mx); sum += l[i2]; }
        sum += __shfl_xor(sum, 16);
        sum += __shfl_xor(sum, 32);
        float inv = inimg ? (1.f / sum) : 0.f;
        unsigned char* base = att + pa * 128;
        int swz = (pa & 7) << 4;
#pragma unroll
        for (int mt = 0; mt < 4; ++mt) {
          uint2 st = { pack2(l[mt * 4 + 0] * inv, l[mt * 4 + 1] * inv),
                       pack2(l[mt * 4 + 2] * inv, l[mt * 4 + 3] * inv) };
          *(uint2*)(base + ((mt * 32 + g * 8) ^ swz)) = st;
        }
      } else {
        float l0 = acc[ti][0][0], l1 = acc[ti][0][1];
        float l2 = acc[ti][0][2], l3 = acc[ti][0][3];
        float mx = fmaxf(fmaxf(l0, l1), fmaxf(l2, l3));
        mx = fmaxf(mx, __shfl_xor(mx, 16));      // g0<->g1 (m 0..7)
        l0 = __expf(l0 - mx); l1 = __expf(l1 - mx);
        l2 = __expf(l2 - mx); l3 = __expf(l3 - mx);
        float sum = l0 + l1 + l2 + l3;
        sum += __shfl_xor(sum, 16);
        float inv = inimg ? (1.f / sum) : 0.f;
        if (g < 2) {                              // m = g*4 + r
          uint2 st = { pack2(l0 * inv, l1 * inv), pack2(l2 * inv, l3 * inv) };
          *(uint2*)(att + pa * 16 + g * 8) = st;
        }
      }
    }
  }

  // ---- read phase: wave w owns rows 2w, 2w+1; single-buffered A ----
  f32x4 racc[2][NRACC];
#pragma unroll
  for (int r = 0; r < 2; ++r)
#pragma unroll
    for (int q = 0; q < NRACC; ++q) racc[r][q] = (f32x4){0.f, 0.f, 0.f, 0.f};

  for (int ch = 0; ch < NCH; ++ch) {
    __syncthreads();                 // att visible (ch=0) / rbuf reads done
    if (tid < RLD) {
      *((uint4*)rbuf + tid) = rreg;
      if (ch + 1 < NCH)
        rreg = *((const uint4*)(readA + (size_t)(ch + 1) * (RCHB / 2)) + tid);
    }
    __syncthreads();
    const unsigned char* ab = rbuf;
    if constexpr (BG) {
#pragma unroll
      for (int l = 0; l < 2; ++l) {
        int uv = 2 * ch + l;
        int uvc = (uv > P * P - 1) ? (P * P - 1) : uv;
        int u = uvc / P, v = uvc - u * P;
#pragma unroll
        for (int r = 0; r < 2; ++r) {
          int pix = (2 * w + r + u) * THX + (col + v);
          int swz = (pix & 7) << 4;
#pragma unroll
          for (int ck = 0; ck < 2; ++ck) {
            f16x8 bb = *(const f16x8*)(att + pix * 128 + ((ck * 64 + g * 16) ^ swz));
            f16x8 ah = *(const f16x8*)(ab + (l * 4 + ck * 2 + 0) * 1024 + col * 64 +
                                       ((g ^ (col & 3)) << 4));
            f16x8 al = *(const f16x8*)(ab + (l * 4 + ck * 2 + 1) * 1024 + col * 64 +
                                       ((g ^ (col & 3)) << 4));
            racc[r][ck * 2 + 0] = __builtin_amdgcn_mfma_f32_16x16x32_f16(ah, bb, racc[r][ck * 2 + 0], 0, 0, 0);
            racc[r][ck * 2 + 1] = __builtin_amdgcn_mfma_f32_16x16x32_f16(al, bb, racc[r][ck * 2 + 1], 0, 0, 0);
          }
        }
      }
    } else {
      int uv = 4 * ch + g;                        // lane's g = K-slot q
      if (uv > P * P - 1) uv = P * P - 1;         // pad: zero A rows
      int u = uv / P, v = uv - u * P;
      int aoff = col * 64 + ((g ^ (col & 3)) << 4);
      f16x8 ah = *(const f16x8*)(ab + aoff);
      f16x8 al = *(const f16x8*)(ab + 1024 + aoff);
#pragma unroll
      for (int r = 0; r < 2; ++r) {
        int pix = (2 * w + r + u) * THX + (col + v);
        f16x8 bb = *(const f16x8*)(att + pix * 16);
        racc[r][0] = __builtin_amdgcn_mfma_f32_16x16x32_f16(ah, bb, racc[r][0], 0, 0, 0);
        racc[r][1] = __builtin_amdgcn_mfma_f32_16x16x32_f16(al, bb, racc[r][1], 0, 0, 0);
      }
    }
  }

  // ---- epilogue: divisor + store + pooled partial (shfl tree) ----
#pragma unroll
  for (int r = 0; r < 2; ++r) {
    f32x4 sv;
    if constexpr (BG) sv = (racc[r][0] + racc[r][1]) + (racc[r][2] + racc[r][3]);
    else              sv = racc[r][0] + racc[r][1];
    int gy = y0 + 2 * w + r, gx = x0 + col;
    int cy = min(P - 1, gy + PAD) - max(0, gy + PAD - (Hdim - 1)) + 1;
    int cx = min(P - 1, gx + PAD) - max(0, gx + PAD - (Wdim - 1)) + 1;
    float inv = 1.f / ((float)(cy * cx) + 1e-8f);
    float o0 = sv[0] * inv, o1 = sv[1] * inv, o2 = sv[2] * inv, o3 = sv[3] * inv;
    float* outp = fout + (size_t)(g * 4) * HWdim + gy * Wdim + gx;
    outp[0] = o0;
    outp[(size_t)1 * HWdim] = o1;
    outp[(size_t)2 * HWdim] = o2;
    outp[(size_t)3 * HWdim] = o3;

    float s0 = o0, s1 = o1, s2 = o2, s3 = o3;
#pragma unroll
    for (int mask = 1; mask < 16; mask <<= 1) {
      s0 += __shfl_xor(s0, mask);
      s1 += __shfl_xor(s1, mask);
      s2 += __shfl_xor(s2, mask);
      s3 += __shfl_xor(s3, mask);
    }
    if (col == 0) {
      float* rp = pscr + ((2 * w + r) * 4 + g) * 4;
      rp[0] = s0; rp[1] = s1; rp[2] = s2; rp[3] = s3;
    }
  }
  __syncthreads();                           // pool scratch ready
  if (tid < 16) {                            // c = tid = g*4+r
    float t = 0.f;
#pragma unroll
    for (int ww = 0; ww < 16; ++ww) t += pscr[ww * 16 + tid];
    gadd(poolp + tid, t * (1.0f / (float)HWdim));
  }
}

__global__ __launch_bounds__(512, 4) void k_fused(FusedArgs a) {
  __shared__ __align__(16) unsigned char smem[FX_SMEM];
  const int z = blockIdx.z;
  const int x0 = blockIdx.x * 16, y0 = blockIdx.y * 16;
  const int tid = threadIdx.x;
  if (z < 6) {
    const int si = z >> 1, b = z & 1;
    const unsigned* xp = a.xpad2 + (size_t)(b * 8) * XPL;
    float* pp = a.pooled + b * 16;
    if (si == 0)
      fused_body<7, true>(xp, a.simA[0], a.readA[0], a.fbgs[0] + (size_t)b * CHW, pp, smem, tid, x0, y0);
    else if (si == 1)
      fused_body<5, true>(xp, a.simA[1], a.readA[1], a.fbgs[1] + (size_t)b * CHW, pp, smem, tid, x0, y0);
    else
      fused_body<3, true>(xp, a.simA[2], a.readA[2], a.fbgs[2] + (size_t)b * CHW, pp, smem, tid, x0, y0);
  } else {
    const int zz = z - 6, si = zz >> 1, b = zz & 1;
    const unsigned* xp = a.xpad2 + (size_t)((2 + b) * 8) * XPL;
    float* pp = a.pooled + 32 + b * 16;
    if (si == 0)
      fused_body<7, false>(xp, a.simAtg[0], a.readAtg[0], a.ftgs[0] + (size_t)b * CHW, pp, smem, tid, x0, y0);
    else if (si == 1)
      fused_body<5, false>(xp, a.simAtg[1], a.readAtg[1], a.ftgs[1] + (size_t)b * CHW, pp, smem, tid, x0, y0);
    else
      fused_body<3, false>(xp, a.simAtg[2], a.readAtg[2], a.ftgs[2] + (size_t)b * CHW, pp, smem, tid, x0, y0);
  }
}

// ---------------------------------------------------------------------------
// Output blend with inlined fusion MLP (per-block recompute from pooled).
// 1024 blocks x 256 thr; each thread handles one float4 quad.
// ---------------------------------------------------------------------------
__global__ __launch_bounds__(256) void k_out(
    const float* __restrict__ fbg, const float* __restrict__ ftg,
    const float* __restrict__ pooled,
    const float* __restrict__ w1b, const float* __restrict__ b1b,
    const float* __restrict__ w2b, const float* __restrict__ b2b,
    const float* __restrict__ w1t, const float* __restrict__ b1t,
    const float* __restrict__ w2t, const float* __restrict__ b2t,
    float* __restrict__ out)
{
  __shared__ float hdn[2][2][4];
  __shared__ float lgs[2][2][48];
  __shared__ float swt[12][16];
  const int t = threadIdx.x;
  if (t < 16) {                 // br=t>>3, b=(t>>2)&1, h=t&3
    int br = t >> 3, b = (t >> 2) & 1, h = t & 3;
    const float* w1 = br ? w1t : w1b;
    const float* b1 = br ? b1t : b1b;
    float s = b1[h];
    for (int c = 0; c < C_CH; ++c) s += pooled[br * 32 + b * 16 + c] * w1[h * 16 + c];
    hdn[br][b][h] = fmaxf(s, 0.f);
  }
  __syncthreads();
  if (t < 192) {                // br=t/96, b, j
    int br = t / 96, r = t - br * 96, b = r / 48, j = r - b * 48;
    const float* w2 = br ? w2t : w2b;
    const float* b2 = br ? b2t : b2b;
    float s = b2[j];
    for (int h = 0; h < 4; ++h) s += hdn[br][b][h] * w2[j * 4 + h];
    lgs[br][b][j] = s;
  }
  __syncthreads();
  if (t < 64) {                 // br=t>>5, b=(t>>4)&1, c=t&15
    int br = t >> 5, b = (t >> 4) & 1, c = t & 15;
    float l0 = lgs[br][b][c], l1 = lgs[br][b][16 + c], l2 = lgs[br][b][32 + c];
    float m = fmaxf(l0, fmaxf(l1, l2));
    float e0 = __expf(l0 - m), e1 = __expf(l1 - m), e2 = __expf(l2 - m);
    float inv = 1.f / (e0 + e1 + e2);
    swt[(br * 2 + b) * 3 + 0][c] = e0 * inv;
    swt[(br * 2 + b) * 3 + 1][c] = e1 * inv;
    swt[(br * 2 + b) * 3 + 2][c] = e2 * inv;
  }
  __syncthreads();

  int base = (blockIdx.x * 256 + t) * 4;         // quad base, 0..2^20
  int br  = base >> 19;
  int rem = base & ((1 << 19) - 1);
  int b   = rem >> 18;
  int off = rem & ((1 << 18) - 1);
  int c   = off >> 14;
  const float* f = (br == 0) ? fbg : ftg;
  int wb = (br * 2 + b) * 3;
  f32x4 acc = {0.f, 0.f, 0.f, 0.f};
#pragma unroll
  for (int s = 0; s < 3; ++s) {
    f32x4 v = *(const f32x4*)(f + (size_t)(s * 2 + b) * CHW + off);
    float wv = swt[wb + s][c];
    acc = __builtin_elementwise_fma((f32x4){wv, wv, wv, wv}, v, acc);
  }
  *(f32x4*)(out + base) = acc;
}

// ---------------------------------------------------------------------------
extern "C" void kernel_launch(void* const* d_in, const int* in_sizes, int n_in,
                              void* d_out, int out_size, void* d_ws, size_t ws_size,
                              hipStream_t stream)
{
  const float* bg = (const float*)d_in[0];
  const float* tg = (const float*)d_in[1];
  const float* bg_mem[3]  = {(const float*)d_in[2],  (const float*)d_in[6],  (const float*)d_in[10]};
  const float* tg_mem[3]  = {(const float*)d_in[3],  (const float*)d_in[7],  (const float*)d_in[11]};
  const float* bg_temp[3] = {(const float*)d_in[4],  (const float*)d_in[8],  (const float*)d_in[12]};
  const float* tg_temp[3] = {(const float*)d_in[5],  (const float*)d_in[9],  (const float*)d_in[13]};
  const float* bg_fc1_w = (const float*)d_in[14];
  const float* bg_fc1_b = (const float*)d_in[15];
  const float* bg_fc2_w = (const float*)d_in[16];
  const float* bg_fc2_b = (const float*)d_in[17];
  const float* tg_fc1_w = (const float*)d_in[18];
  const float* tg_fc1_b = (const float*)d_in[19];
  const float* tg_fc2_w = (const float*)d_in[20];
  const float* tg_fc2_b = (const float*)d_in[21];

  unsigned* ws = (unsigned*)d_ws;
  unsigned* xpad2   = ws;                                    // 627,200 u32
  float*    pooled  = (float*)(ws + (size_t)32 * XPL);       // 64
  float*    wt      = pooled + 64;                           // 192 (unused pad)
  _Float16* simA    = (_Float16*)(wt + 192);                 // 176,128 halfs
  _Float16* readA   = simA + 176128;                         // 176,128 halfs
  _Float16* simAtg  = readA + 176128;                        // 44,032 halfs
  _Float16* readAtg = simAtg + 44032;                        // 23,552 halfs
  float*    ftg     = (float*)(readAtg + 23552);             // 6*CHW
  float*    fbg     = ftg + (size_t)6 * CHW;                 // 6*CHW

  // zero xpad2 border + pooled + all A arrays (pad slots) in one shot
  hipMemsetAsync(xpad2, 0, (size_t)837376 * 4, stream);

  const int   Ms[6] = {64, 64, 64, 8, 8, 8};
  const int   Ps[6] = {3, 5, 7, 3, 5, 7};
  const float* mems[6]  = {bg_mem[0], bg_mem[1], bg_mem[2], tg_mem[0], tg_mem[1], tg_mem[2]};
  const float* temps[6] = {bg_temp[0], bg_temp[1], bg_temp[2], tg_temp[0], tg_temp[1], tg_temp[2]};

  // per-scale offsets (halfs), si 0..2 = P7,P5,P3
  const size_t aOff[3]   = {0, 102400, 155648};   // bg sim & read (same sizes)
  const size_t sOffTg[3] = {0, 25600, 38912};     // tg sim
  const size_t rOffTg[3] = {0, 13312, 20480};     // tg read

  PrepArgs pa;
  for (int k = 0; k < 6; ++k) {
    int D = C_CH * Ps[k] * Ps[k];
    int si = 2 - (k % 3);                         // PS index -> scale index
    if (k < 3)
      pa.d[k] = {mems[k], temps[k], simA + aOff[si], readA + aOff[si],
                 Ms[k], D, Ps[k], 0};
    else
      pa.d[k] = {mems[k], temps[k], simAtg + sOffTg[si], readAtg + rOffTg[si],
                 Ms[k], D, Ps[k], 1};
  }
  k_preppad<<<3224, 256, 0, stream>>>(pa, bg, tg, xpad2);

  FusedArgs fa;
  fa.xpad2 = xpad2;
  fa.pooled = pooled;
  for (int si = 0; si < 3; ++si) {
    int p = 2 - si;
    fa.simA[si]    = simA + aOff[si];
    fa.readA[si]   = readA + aOff[si];
    fa.simAtg[si]  = simAtg + sOffTg[si];
    fa.readAtg[si] = readAtg + rOffTg[si];
    fa.fbgs[si]    = fbg + (size_t)p * 2 * CHW;
    fa.ftgs[si]    = ftg + (size_t)p * 2 * CHW;
  }

  k_fused<<<dim3(8, 8, 12), 512, 0, stream>>>(fa);

  k_out<<<1024, 256, 0, stream>>>(fbg, ftg, pooled,
                                  bg_fc1_w, bg_fc1_b, bg_fc2_w, bg_fc2_b,
                                  tg_fc1_w, tg_fc1_b, tg_fc2_w, tg_fc2_b,
                                  (float*)d_out);
}

// Round 11
// 157.690 us; speedup vs baseline: 1.2745x; 1.0205x over previous
//
#include <hip/hip_runtime.h>

#define C_CH 16
#define Hdim 128
#define Wdim 128
#define HWdim 16384
#define CHW (C_CH * HWdim)                 // 262144 floats: one [C][H][W] slab
#define Bdim 2
#define PAIR_ELEMS (Bdim * CHW)            // 524288

// x canvas: border 6 (= 2*max PAD, fused kernel needs double halo)
#define XWP 140
#define XHP 140
#define XPL (XHP * XWP)                    // 19600 per pair-plane

typedef float v2f __attribute__((ext_vector_type(2)));
typedef _Float16 h2 __attribute__((ext_vector_type(2)));
typedef _Float16 f16x8 __attribute__((ext_vector_type(8)));
typedef float f32x4 __attribute__((ext_vector_type(4)));

__device__ __forceinline__ unsigned pack2(float a, float b) {
  h2 h = {(_Float16)a, (_Float16)b};
  return __builtin_bit_cast(unsigned, h);
}
__device__ __forceinline__ void gadd(float* p, float v) {
  __hip_atomic_fetch_add(p, v, __ATOMIC_RELAXED, __HIP_MEMORY_SCOPE_AGENT);
}

// ---------------------------------------------------------------------------
// Prep layouts (MFMA A-operands, hi+lo f16 split, LDS-swizzled form)
// bg simA  [uvp][s(2)][mt(4)][row16][k32 swz]   scaled   (4096 halfs/uvp)
//          allocated NUVP+1 uvp (pad uvp zeroed; sim chunks stage 2 uvp)
// bg readA [uvf][ck(2)][s(2)][c16][k32 swz]     unscaled (flipped; P*P+1 slots)
// tg simA  [uvp][s(2)][row16(m<8)][k32 swz]     scaled   (1024 halfs/uvp, +pad)
// tg readA [ch][s(2)][c16][k32 swz] k=q*8+m     unscaled (flipped)
// k-swizzle: halfs offset (kg ^ (row&3))*8 + kl  -> conflict-free A reads
// ---------------------------------------------------------------------------
struct PrepDesc {
  const float* mem;
  const float* temp;
  _Float16* simA;
  _Float16* readA;
  int M, D, P, tg;
};
struct PrepArgs { PrepDesc d[6]; };

// merged prep + padx: blocks [0,2048) build the x canvas, [2048,3224) prep A
__global__ __launch_bounds__(256) void k_preppad(PrepArgs a,
                                                 const float* __restrict__ bg,
                                                 const float* __restrict__ tg,
                                                 unsigned* __restrict__ xpad2)
{
  int bid = blockIdx.x;
  if (bid < 2048) {
    int idx = bid * 256 + threadIdx.x;          // 32 pair-planes * HW
    int pp = idx >> 14;
    int hw = idx & (HWdim - 1);
    int y = hw >> 7, x = hw & 127;
    int z = pp >> 3, cp = pp & 7;
    const float* src = (z < 2) ? bg : tg;
    int b = z & 1;
    float av = src[((b * C_CH + 2 * cp) << 14) + hw];
    float bv = src[((b * C_CH + 2 * cp + 1) << 14) + hw];
    xpad2[(size_t)pp * XPL + (y + 6) * XWP + (x + 6)] = pack2(av, bv);
    return;
  }
  int p = bid - 2048;                           // 0..1175 = (196 x, 6 y)
  int gy = p / 196, gx = p - gy * 196;
  PrepDesc de = a.d[gy];
  int n = de.M * de.D;
  int idx = gx * 256 + threadIdx.x;
  if (idx >= n) return;
  int m = idx / de.D;
  int d = idx - m * de.D;
  float val = de.mem[idx];
  float sc = de.temp[0] / sqrtf((float)de.D);
  int pp = de.P * de.P;
  int c = d / pp;
  int r = d - c * pp;
  int i = r / de.P;
  int j = r - i * de.P;
  int uv = i * de.P + j;                 // unflipped (sim correlation)
  int uvp = uv >> 1, luv = uv & 1;
  int kk = luv * 16 + c, kg = kk >> 3, kl = kk & 7;
  int u = de.P - 1 - i, v = de.P - 1 - j;
  int uvf = u * de.P + v;                // flipped (read fold)
  float sv = val * sc;
  if (!de.tg) {
    int mt = m >> 4, row = m & 15;
    _Float16 hi = (_Float16)sv;
    size_t bi = ((size_t)uvp * 8 + mt) * 512 + row * 32 +
                (size_t)((kg ^ (row & 3)) * 8 + kl);
    de.simA[bi] = hi;
    de.simA[bi + 2048] = (_Float16)(sv - (float)hi);
    int ck = m >> 5, m5 = m & 31, kg2 = m5 >> 3, kl2 = m5 & 7;
    _Float16 hr = (_Float16)val;
    size_t b2 = (size_t)uvf * 2048 + (size_t)(ck * 2) * 512 + c * 32 +
                (size_t)((kg2 ^ (c & 3)) * 8 + kl2);
    de.readA[b2] = hr;
    de.readA[b2 + 512] = (_Float16)(val - (float)hr);
  } else {
    _Float16 hi = (_Float16)sv;          // m in 0..7, rows 8..15 stay zero
    size_t bi = (size_t)(uvp * 2) * 512 + m * 32 +
                (size_t)((kg ^ (m & 3)) * 8 + kl);
    de.simA[bi] = hi;
    de.simA[bi + 512] = (_Float16)(sv - (float)hi);
    int ch = uvf >> 2, q = uvf & 3;
    _Float16 hr = (_Float16)val;
    size_t b2 = (size_t)ch * 1024 + c * 32 +
                (size_t)((q ^ (c & 3)) * 8 + (m & 7));
    de.readA[b2] = hr;
    de.readA[b2 + 512] = (_Float16)(val - (float)hr);
  }
}

// ---------------------------------------------------------------------------
// Fully fused sim + softmax + read (+ pooled partial) for bg AND tg.
// Block = 16x16 out px, 512 thr. LDS 80896 B, 2 blocks/CU:
//   [0,25088)      x-halo [h][pix][16B]          (sim phase)
//   [25088,57856)  sim A double buffer 2x16KB    (2 uvp/chunk)
//   [0,63488)      att (bg 128B/px swz, tg 16B)  (read phase; aliases both)
//   [63488,79872)  read A double buffer 2x8KB
//   [79872,80896)  pooled scratch
// Sim: 1 barrier / 2-uvp chunk. Read: 1 barrier/chunk (dbuf, prefetch
// overlapped). Pad uv slots have zero-A (alloc zeroed); BOTH uva and uvb
// are clamped to P*P-1 so B addresses stay in the WRITTEN halo region
// (r10 bug: unclamped uva read stale LDS -> f16 NaN patterns -> 0*NaN).
// z: 0..5 bg (si*2+b), 6..11 tg. si 0..2 = {P7,P5,P3}.
// NOTE: (512,4) — do NOT raise min-waves (r6: spill); do NOT move A to
// global (r8: latency-bound).
// ---------------------------------------------------------------------------
struct FusedArgs {
  const unsigned* xpad2;
  const _Float16* simA[3];
  const _Float16* readA[3];
  const _Float16* simAtg[3];
  const _Float16* readAtg[3];
  float* fbgs[3];
  float* ftgs[3];
  float* pooled;
};

#define SDB_OFF 25088
#define RBUF_OFF 63488
#define PSCR_OFF 79872
#define FX_SMEM 80896

template<int P, bool BG>
__device__ __forceinline__ void fused_body(
    const unsigned* __restrict__ xp,          // + plane base
    const _Float16* __restrict__ simA,
    const _Float16* __restrict__ readA,
    float* __restrict__ fout,                 // + b*CHW
    float* __restrict__ poolp,                // pooled + branch/b base
    unsigned char* smem, int tid, int x0, int y0)
{
  constexpr int PAD = P / 2;
  constexpr int THY = 16 + 2 * PAD, THX = 16 + 2 * PAD;  // att halo
  constexpr int XH = 16 + 4 * PAD, XW = 16 + 4 * PAD;    // x halo
  constexpr int NXP = XH * XW, NHP = THY * THX;
  constexpr int NT = (NHP + 15) / 16;
  constexpr int NUVP = (P * P + 1) / 2;
  constexpr int NSCH = (NUVP + 1) / 2;       // sim chunks (2 uvp each)
  constexpr int NCH = BG ? (P * P + 1) / 2 : (P * P + 3) / 4;
  constexpr int NMT = BG ? 4 : 1;
  constexpr int SCHB = BG ? 8192 : 2048;     // sim A bytes per uvp
  constexpr int SCHB2 = 2 * SCHB;            // sim A chunk bytes (2 uvp)
  constexpr int RCHB = BG ? 8192 : 2048;     // read A chunk bytes
  constexpr int SST = SCHB2 / 32;            // sim staging threads (2 uint4)
  constexpr int RLD = RCHB / 16;             // read staging threads (1 uint4)
  constexpr int NRACC = BG ? 4 : 2;
  constexpr int NTI = 4;                     // sim N-tiles per wave

  unsigned char* xbuf = smem;                // sim phase
  unsigned char* att  = smem;                // read phase (aliases xbuf+sdb)
  unsigned char* sdb  = smem + SDB_OFF;      // sim A dbuf (2 x SCHB2)
  unsigned char* rdb  = smem + RBUF_OFF;     // read A dbuf (2 x RCHB)
  float* pscr = (float*)(smem + PSCR_OFF);

  const int w = __builtin_amdgcn_readfirstlane(tid >> 6);
  const int lane = tid & 63;
  const int col = lane & 15, g = lane >> 4;

  // ---- stage x halo as [h][pix][16B] (c = h*8..h*8+7), b128 writes ----
  const int oy = y0 - 2 * PAD + 6, ox = x0 - 2 * PAD + 6;
  for (int t = tid; t < 2 * NXP; t += 512) {
    int h = (t >= NXP) ? 1 : 0;
    int pix = t - h * NXP;
    int ly = pix / XW, lx = pix - ly * XW;
    const unsigned* s = xp + (size_t)(h * 4) * XPL + (oy + ly) * XWP + (ox + lx);
    uint4 vv = { s[0], s[XPL], s[2 * XPL], s[3 * XPL] };
    *(uint4*)(xbuf + (h * NXP + pix) * 16) = vv;
  }

  // ---- per-tile pixel coords (wave w: tiles w, w+8, w+16, w+24) ----
  int ayv[NTI], axv[NTI];
#pragma unroll
  for (int ti = 0; ti < NTI; ++ti) {
    int nt = w + ti * 8;
    int pix = nt * 16 + col;
    if (pix > NHP - 1) pix = NHP - 1;
    ayv[ti] = pix / THX;
    axv[ti] = pix - ayv[ti] * THX;
  }

  f32x4 acc[NTI][NMT];
#pragma unroll
  for (int ti = 0; ti < NTI; ++ti)
#pragma unroll
    for (int mt = 0; mt < NMT; ++mt) acc[ti][mt] = (f32x4){0.f, 0.f, 0.f, 0.f};

  // ---- sim K-loop: 2-uvp chunks, double-buffered A, 1 barrier/chunk ----
  uint4 s0, s1;
  if (tid < SST) {
    const uint4* p = (const uint4*)simA + tid * 2;
    s0 = p[0]; s1 = p[1];
  }
  for (int c = 0; c < NSCH; ++c) {
    if (tid < SST) {
      uint4* q = (uint4*)(sdb + (c & 1) * SCHB2) + tid * 2;
      q[0] = s0; q[1] = s1;
      if (c + 1 < NSCH) {
        const uint4* p = (const uint4*)(simA + (size_t)(c + 1) * (SCHB2 / 2)) + tid * 2;
        s0 = p[0]; s1 = p[1];
      }
    }
    __syncthreads();

#pragma unroll
    for (int l = 0; l < 2; ++l) {
      const int uvp = 2 * c + l;
      const unsigned char* ab = sdb + (c & 1) * SCHB2 + l * SCHB;
      f16x8 af[2][NMT];
#pragma unroll
      for (int s = 0; s < 2; ++s)
#pragma unroll
        for (int mt = 0; mt < NMT; ++mt)
          af[s][mt] = *(const f16x8*)(ab + (s * NMT + mt) * 1024 + col * 64 +
                                      ((g ^ (col & 3)) << 4));

      // pad slots (uva/uvb >= P*P) have zero A; clamp BOTH so the B
      // address stays inside the written halo (r10 NaN fix).
      int uva = 2 * uvp;
      int uvb = uva + 1;
      if (uva >= P * P) uva = P * P - 1;
      if (uvb >= P * P) uvb = P * P - 1;
      const int ua = uva / P, va = uva - ua * P;
      const int ub = uvb / P, vb = uvb - ub * P;
      const int u_ = (g >= 2) ? ub : ua;
      const int v_ = (g >= 2) ? vb : va;

#pragma unroll
      for (int ti = 0; ti < NTI; ++ti) {
        int nt = w + ti * 8;
        if (nt < NT) {
          int xpix = (ayv[ti] + u_) * XW + axv[ti] + v_;
          f16x8 bb = *(const f16x8*)(xbuf + ((g & 1) * NXP + xpix) * 16);
#pragma unroll
          for (int mt = 0; mt < NMT; ++mt) {
            acc[ti][mt] = __builtin_amdgcn_mfma_f32_16x16x32_f16(af[0][mt], bb, acc[ti][mt], 0, 0, 0);
            acc[ti][mt] = __builtin_amdgcn_mfma_f32_16x16x32_f16(af[1][mt], bb, acc[ti][mt], 0, 0, 0);
          }
        }
      }
    }
  }

  // prefetch first read-A chunk; fence xbuf/sdb reads before att overwrites
  uint4 rreg;
  if (tid < RLD) rreg = *((const uint4*)readA + tid);
  __syncthreads();

  // ---- softmax + att store to LDS (att aliases xbuf+sdb region) ----
#pragma unroll
  for (int ti = 0; ti < NTI; ++ti) {
    int nt = w + ti * 8;
    if (nt < NT) {
      int pa = nt * 16 + col;
      int say = pa / THX, sax = pa - say * THX;
      int gy = y0 + say - PAD, gx = x0 + sax - PAD;
      bool inimg = (pa < NHP) & (gy >= 0) & (gy < Hdim) & (gx >= 0) & (gx < Wdim);
      if constexpr (BG) {
        float l[16];
#pragma unroll
        for (int mt = 0; mt < 4; ++mt)
#pragma unroll
          for (int r = 0; r < 4; ++r) l[mt * 4 + r] = acc[ti][mt][r];
        float mx = l[0];
#pragma unroll
        for (int i2 = 1; i2 < 16; ++i2) mx = fmaxf(mx, l[i2]);
        mx = fmaxf(mx, __shfl_xor(mx, 16));
        mx = fmaxf(mx, __shfl_xor(mx, 32));
        float sum = 0.f;
#pragma unroll
        for (int i2 = 0; i2 < 16; ++i2) { l[i2] = __expf(l[i2] - mx); sum += l[i2]; }
        sum += __shfl_xor(sum, 16);
        sum += __shfl_xor(sum, 32);
        float inv = inimg ? (1.f / sum) : 0.f;
        unsigned char* base = att + pa * 128;
        int swz = (pa & 7) << 4;
#pragma unroll
        for (int mt = 0; mt < 4; ++mt) {
          uint2 st = { pack2(l[mt * 4 + 0] * inv, l[mt * 4 + 1] * inv),
                       pack2(l[mt * 4 + 2] * inv, l[mt * 4 + 3] * inv) };
          *(uint2*)(base + ((mt * 32 + g * 8) ^ swz)) = st;
        }
      } else {
        float l0 = acc[ti][0][0], l1 = acc[ti][0][1];
        float l2 = acc[ti][0][2], l3 = acc[ti][0][3];
        float mx = fmaxf(fmaxf(l0, l1), fmaxf(l2, l3));
        mx = fmaxf(mx, __shfl_xor(mx, 16));      // g0<->g1 (m 0..7)
        l0 = __expf(l0 - mx); l1 = __expf(l1 - mx);
        l2 = __expf(l2 - mx); l3 = __expf(l3 - mx);
        float sum = l0 + l1 + l2 + l3;
        sum += __shfl_xor(sum, 16);
        float inv = inimg ? (1.f / sum) : 0.f;
        if (g < 2) {                              // m = g*4 + r
          uint2 st = { pack2(l0 * inv, l1 * inv), pack2(l2 * inv, l3 * inv) };
          *(uint2*)(att + pa * 16 + g * 8) = st;
        }
      }
    }
  }

  // ---- read phase: wave w owns rows 2w, 2w+1; double-buffered A ----
  f32x4 racc[2][NRACC];
#pragma unroll
  for (int r = 0; r < 2; ++r)
#pragma unroll
    for (int q = 0; q < NRACC; ++q) racc[r][q] = (f32x4){0.f, 0.f, 0.f, 0.f};

  for (int ch = 0; ch < NCH; ++ch) {
    if (tid < RLD) {
      *((uint4*)(rdb + (ch & 1) * RCHB) + tid) = rreg;
      if (ch + 1 < NCH)
        rreg = *((const uint4*)(readA + (size_t)(ch + 1) * (RCHB / 2)) + tid);
    }
    __syncthreads();                 // staged visible; att ready at ch==0
    const unsigned char* ab = rdb + (ch & 1) * RCHB;
    if constexpr (BG) {
#pragma unroll
      for (int l = 0; l < 2; ++l) {
        int uv = 2 * ch + l;
        int uvc = (uv > P * P - 1) ? (P * P - 1) : uv;
        int u = uvc / P, v = uvc - u * P;
#pragma unroll
        for (int r = 0; r < 2; ++r) {
          int pix = (2 * w + r + u) * THX + (col + v);
          int swz = (pix & 7) << 4;
#pragma unroll
          for (int ck = 0; ck < 2; ++ck) {
            f16x8 bb = *(const f16x8*)(att + pix * 128 + ((ck * 64 + g * 16) ^ swz));
            f16x8 ah = *(const f16x8*)(ab + (l * 4 + ck * 2 + 0) * 1024 + col * 64 +
                                       ((g ^ (col & 3)) << 4));
            f16x8 al = *(const f16x8*)(ab + (l * 4 + ck * 2 + 1) * 1024 + col * 64 +
                                       ((g ^ (col & 3)) << 4));
            racc[r][ck * 2 + 0] = __builtin_amdgcn_mfma_f32_16x16x32_f16(ah, bb, racc[r][ck * 2 + 0], 0, 0, 0);
            racc[r][ck * 2 + 1] = __builtin_amdgcn_mfma_f32_16x16x32_f16(al, bb, racc[r][ck * 2 + 1], 0, 0, 0);
          }
        }
      }
    } else {
      int uv = 4 * ch + g;                        // lane's g = K-slot q
      if (uv > P * P - 1) uv = P * P - 1;         // pad: zero A rows
      int u = uv / P, v = uv - u * P;
      int aoff = col * 64 + ((g ^ (col & 3)) << 4);
      f16x8 ah = *(const f16x8*)(ab + aoff);
      f16x8 al = *(const f16x8*)(ab + 1024 + aoff);
#pragma unroll
      for (int r = 0; r < 2; ++r) {
        int pix = (2 * w + r + u) * THX + (col + v);
        f16x8 bb = *(const f16x8*)(att + pix * 16);
        racc[r][0] = __builtin_amdgcn_mfma_f32_16x16x32_f16(ah, bb, racc[r][0], 0, 0, 0);
        racc[r][1] = __builtin_amdgcn_mfma_f32_16x16x32_f16(al, bb, racc[r][1], 0, 0, 0);
      }
    }
  }

  // ---- epilogue: divisor + store + pooled partial (shfl tree) ----
#pragma unroll
  for (int r = 0; r < 2; ++r) {
    f32x4 sv;
    if constexpr (BG) sv = (racc[r][0] + racc[r][1]) + (racc[r][2] + racc[r][3]);
    else              sv = racc[r][0] + racc[r][1];
    int gy = y0 + 2 * w + r, gx = x0 + col;
    int cy = min(P - 1, gy + PAD) - max(0, gy + PAD - (Hdim - 1)) + 1;
    int cx = min(P - 1, gx + PAD) - max(0, gx + PAD - (Wdim - 1)) + 1;
    float inv = 1.f / ((float)(cy * cx) + 1e-8f);
    float o0 = sv[0] * inv, o1 = sv[1] * inv, o2 = sv[2] * inv, o3 = sv[3] * inv;
    float* outp = fout + (size_t)(g * 4) * HWdim + gy * Wdim + gx;
    outp[0] = o0;
    outp[(size_t)1 * HWdim] = o1;
    outp[(size_t)2 * HWdim] = o2;
    outp[(size_t)3 * HWdim] = o3;

    float s0v = o0, s1v = o1, s2v = o2, s3v = o3;
#pragma unroll
    for (int mask = 1; mask < 16; mask <<= 1) {
      s0v += __shfl_xor(s0v, mask);
      s1v += __shfl_xor(s1v, mask);
      s2v += __shfl_xor(s2v, mask);
      s3v += __shfl_xor(s3v, mask);
    }
    if (col == 0) {
      float* rp = pscr + ((2 * w + r) * 4 + g) * 4;
      rp[0] = s0v; rp[1] = s1v; rp[2] = s2v; rp[3] = s3v;
    }
  }
  __syncthreads();                           // pool scratch ready
  if (tid < 16) {                            // c = tid = g*4+r
    float t = 0.f;
#pragma unroll
    for (int ww = 0; ww < 16; ++ww) t += pscr[ww * 16 + tid];
    gadd(poolp + tid, t * (1.0f / (float)HWdim));
  }
}

__global__ __launch_bounds__(512, 4) void k_fused(FusedArgs a) {
  __shared__ __align__(16) unsigned char smem[FX_SMEM];
  const int z = blockIdx.z;
  const int x0 = blockIdx.x * 16, y0 = blockIdx.y * 16;
  const int tid = threadIdx.x;
  if (z < 6) {
    const int si = z >> 1, b = z & 1;
    const unsigned* xp = a.xpad2 + (size_t)(b * 8) * XPL;
    float* pp = a.pooled + b * 16;
    if (si == 0)
      fused_body<7, true>(xp, a.simA[0], a.readA[0], a.fbgs[0] + (size_t)b * CHW, pp, smem, tid, x0, y0);
    else if (si == 1)
      fused_body<5, true>(xp, a.simA[1], a.readA[1], a.fbgs[1] + (size_t)b * CHW, pp, smem, tid, x0, y0);
    else
      fused_body<3, true>(xp, a.simA[2], a.readA[2], a.fbgs[2] + (size_t)b * CHW, pp, smem, tid, x0, y0);
  } else {
    const int zz = z - 6, si = zz >> 1, b = zz & 1;
    const unsigned* xp = a.xpad2 + (size_t)((2 + b) * 8) * XPL;
    float* pp = a.pooled + 32 + b * 16;
    if (si == 0)
      fused_body<7, false>(xp, a.simAtg[0], a.readAtg[0], a.ftgs[0] + (size_t)b * CHW, pp, smem, tid, x0, y0);
    else if (si == 1)
      fused_body<5, false>(xp, a.simAtg[1], a.readAtg[1], a.ftgs[1] + (size_t)b * CHW, pp, smem, tid, x0, y0);
    else
      fused_body<3, false>(xp, a.simAtg[2], a.readAtg[2], a.ftgs[2] + (size_t)b * CHW, pp, smem, tid, x0, y0);
  }
}

// ---------------------------------------------------------------------------
// Output blend with inlined fusion MLP (per-block recompute from pooled).
// 1024 blocks x 256 thr; each thread handles one float4 quad.
// ---------------------------------------------------------------------------
__global__ __launch_bounds__(256) void k_out(
    const float* __restrict__ fbg, const float* __restrict__ ftg,
    const float* __restrict__ pooled,
    const float* __restrict__ w1b, const float* __restrict__ b1b,
    const float* __restrict__ w2b, const float* __restrict__ b2b,
    const float* __restrict__ w1t, const float* __restrict__ b1t,
    const float* __restrict__ w2t, const float* __restrict__ b2t,
    float* __restrict__ out)
{
  __shared__ float hdn[2][2][4];
  __shared__ float lgs[2][2][48];
  __shared__ float swt[12][16];
  const int t = threadIdx.x;
  if (t < 16) {                 // br=t>>3, b=(t>>2)&1, h=t&3
    int br = t >> 3, b = (t >> 2) & 1, h = t & 3;
    const float* w1 = br ? w1t : w1b;
    const float* b1 = br ? b1t : b1b;
    float s = b1[h];
    for (int c = 0; c < C_CH; ++c) s += pooled[br * 32 + b * 16 + c] * w1[h * 16 + c];
    hdn[br][b][h] = fmaxf(s, 0.f);
  }
  __syncthreads();
  if (t < 192) {                // br=t/96, b, j
    int br = t / 96, r = t - br * 96, b = r / 48, j = r - b * 48;
    const float* w2 = br ? w2t : w2b;
    const float* b2 = br ? b2t : b2b;
    float s = b2[j];
    for (int h = 0; h < 4; ++h) s += hdn[br][b][h] * w2[j * 4 + h];
    lgs[br][b][j] = s;
  }
  __syncthreads();
  if (t < 64) {                 // br=t>>5, b=(t>>4)&1, c=t&15
    int br = t >> 5, b = (t >> 4) & 1, c = t & 15;
    float l0 = lgs[br][b][c], l1 = lgs[br][b][16 + c], l2 = lgs[br][b][32 + c];
    float m = fmaxf(l0, fmaxf(l1, l2));
    float e0 = __expf(l0 - m), e1 = __expf(l1 - m), e2 = __expf(l2 - m);
    float inv = 1.f / (e0 + e1 + e2);
    swt[(br * 2 + b) * 3 + 0][c] = e0 * inv;
    swt[(br * 2 + b) * 3 + 1][c] = e1 * inv;
    swt[(br * 2 + b) * 3 + 2][c] = e2 * inv;
  }
  __syncthreads();

  int base = (blockIdx.x * 256 + t) * 4;         // quad base, 0..2^20
  int br  = base >> 19;
  int rem = base & ((1 << 19) - 1);
  int b   = rem >> 18;
  int off = rem & ((1 << 18) - 1);
  int c   = off >> 14;
  const float* f = (br == 0) ? fbg : ftg;
  int wb = (br * 2 + b) * 3;
  f32x4 acc = {0.f, 0.f, 0.f, 0.f};
#pragma unroll
  for (int s = 0; s < 3; ++s) {
    f32x4 v = *(const f32x4*)(f + (size_t)(s * 2 + b) * CHW + off);
    float wv = swt[wb + s][c];
    acc = __builtin_elementwise_fma((f32x4){wv, wv, wv, wv}, v, acc);
  }
  *(f32x4*)(out + base) = acc;
}

// ---------------------------------------------------------------------------
extern "C" void kernel_launch(void* const* d_in, const int* in_sizes, int n_in,
                              void* d_out, int out_size, void* d_ws, size_t ws_size,
                              hipStream_t stream)
{
  const float* bg = (const float*)d_in[0];
  const float* tg = (const float*)d_in[1];
  const float* bg_mem[3]  = {(const float*)d_in[2],  (const float*)d_in[6],  (const float*)d_in[10]};
  const float* tg_mem[3]  = {(const float*)d_in[3],  (const float*)d_in[7],  (const float*)d_in[11]};
  const float* bg_temp[3] = {(const float*)d_in[4],  (const float*)d_in[8],  (const float*)d_in[12]};
  const float* tg_temp[3] = {(const float*)d_in[5],  (const float*)d_in[9],  (const float*)d_in[13]};
  const float* bg_fc1_w = (const float*)d_in[14];
  const float* bg_fc1_b = (const float*)d_in[15];
  const float* bg_fc2_w = (const float*)d_in[16];
  const float* bg_fc2_b = (const float*)d_in[17];
  const float* tg_fc1_w = (const float*)d_in[18];
  const float* tg_fc1_b = (const float*)d_in[19];
  const float* tg_fc2_w = (const float*)d_in[20];
  const float* tg_fc2_b = (const float*)d_in[21];

  unsigned* ws = (unsigned*)d_ws;
  unsigned* xpad2   = ws;                                    // 627,200 u32
  float*    pooled  = (float*)(ws + (size_t)32 * XPL);       // 64
  float*    wt      = pooled + 64;                           // 192 (pad)
  _Float16* simA    = (_Float16*)(wt + 192);                 // 188,416 halfs
  _Float16* readA   = simA + 188416;                         // 176,128 halfs
  _Float16* simAtg  = readA + 176128;                        // 47,104 halfs
  _Float16* readAtg = simAtg + 47104;                        // 23,552 halfs
  float*    ftg     = (float*)(readAtg + 23552);             // 6*CHW
  float*    fbg     = ftg + (size_t)6 * CHW;                 // 6*CHW

  // zero xpad2 border + pooled + all A arrays (incl. pad uvp chunks):
  // 627200 + 64 + 192 + 94208 + 88064 + 23552 + 11776 = 845056 u32
  hipMemsetAsync(xpad2, 0, (size_t)845056 * 4, stream);

  const int   Ms[6] = {64, 64, 64, 8, 8, 8};
  const int   Ps[6] = {3, 5, 7, 3, 5, 7};
  const float* mems[6]  = {bg_mem[0], bg_mem[1], bg_mem[2], tg_mem[0], tg_mem[1], tg_mem[2]};
  const float* temps[6] = {bg_temp[0], bg_temp[1], bg_temp[2], tg_temp[0], tg_temp[1], tg_temp[2]};

  // per-scale offsets (halfs), si 0..2 = P7,P5,P3
  const size_t aOffS[3]  = {0, 106496, 163840};   // bg sim (NUVP+1 uvp each)
  const size_t aOffR[3]  = {0, 102400, 155648};   // bg read (P*P+1 uv slots)
  const size_t sOffTg[3] = {0, 26624, 40960};     // tg sim (NUVP+1 uvp each)
  const size_t rOffTg[3] = {0, 13312, 20480};     // tg read

  PrepArgs pa;
  for (int k = 0; k < 6; ++k) {
    int D = C_CH * Ps[k] * Ps[k];
    int si = 2 - (k % 3);                         // PS index -> scale index
    if (k < 3)
      pa.d[k] = {mems[k], temps[k], simA + aOffS[si], readA + aOffR[si],
                 Ms[k], D, Ps[k], 0};
    else
      pa.d[k] = {mems[k], temps[k], simAtg + sOffTg[si], readAtg + rOffTg[si],
                 Ms[k], D, Ps[k], 1};
  }
  k_preppad<<<3224, 256, 0, stream>>>(pa, bg, tg, xpad2);

  FusedArgs fa;
  fa.xpad2 = xpad2;
  fa.pooled = pooled;
  for (int si = 0; si < 3; ++si) {
    int p = 2 - si;
    fa.simA[si]    = simA + aOffS[si];
    fa.readA[si]   = readA + aOffR[si];
    fa.simAtg[si]  = simAtg + sOffTg[si];
    fa.readAtg[si] = readAtg + rOffTg[si];
    fa.fbgs[si]    = fbg + (size_t)p * 2 * CHW;
    fa.ftgs[si]    = ftg + (size_t)p * 2 * CHW;
  }

  k_fused<<<dim3(8, 8, 12), 512, 0, stream>>>(fa);

  k_out<<<1024, 256, 0, stream>>>(fbg, ftg, pooled,
                                  bg_fc1_w, bg_fc1_b, bg_fc2_w, bg_fc2_b,
                                  tg_fc1_w, tg_fc1_b, tg_fc2_w, tg_fc2_b,
                                  (float*)d_out);
}

// Round 12
// 144.101 us; speedup vs baseline: 1.3947x; 1.0943x over previous
//
#include <hip/hip_runtime.h>

#define C_CH 16
#define Hdim 128
#define Wdim 128
#define HWdim 16384
#define CHW (C_CH * HWdim)                 // 262144 floats: one [C][H][W] slab
#define Bdim 2
#define PAIR_ELEMS (Bdim * CHW)            // 524288

// x canvas: border 6 (= 2*max PAD, fused kernel needs double halo)
#define XWP 140
#define XHP 140
#define XPL (XHP * XWP)                    // 19600 per pair-plane

typedef float v2f __attribute__((ext_vector_type(2)));
typedef _Float16 h2 __attribute__((ext_vector_type(2)));
typedef _Float16 f16x8 __attribute__((ext_vector_type(8)));
typedef float f32x4 __attribute__((ext_vector_type(4)));

__device__ __forceinline__ unsigned pack2(float a, float b) {
  h2 h = {(_Float16)a, (_Float16)b};
  return __builtin_bit_cast(unsigned, h);
}
__device__ __forceinline__ void gadd(float* p, float v) {
  __hip_atomic_fetch_add(p, v, __ATOMIC_RELAXED, __HIP_MEMORY_SCOPE_AGENT);
}

// ---------------------------------------------------------------------------
// Prep layouts (MFMA A-operands, PLAIN f16 weights — r12 dropped the hi/lo
// split: absmax margin was 5.6x and the split doubled MFMA + A traffic)
// bg simA  [uvp][mt(4)][row16][k32 swz]   scaled   (2048 halfs/uvp, +pad uvp)
// bg readA [uvf][ck(2)][c16][k32 swz]     unscaled (flipped; P*P+1 slots)
// tg simA  [uvp][row16(m<8)][k32 swz]     scaled   (512 halfs/uvp, +pad)
// tg readA [ch][c16][k32 swz] k=q*8+m     unscaled (flipped)
// k-swizzle: halfs offset (kg ^ (row&3))*8 + kl  -> conflict-free A reads
// ---------------------------------------------------------------------------
struct PrepDesc {
  const float* mem;
  const float* temp;
  _Float16* simA;
  _Float16* readA;
  int M, D, P, tg;
};
struct PrepArgs { PrepDesc d[6]; };

// merged prep + padx: blocks [0,2048) build the x canvas, [2048,3224) prep A
__global__ __launch_bounds__(256) void k_preppad(PrepArgs a,
                                                 const float* __restrict__ bg,
                                                 const float* __restrict__ tg,
                                                 unsigned* __restrict__ xpad2)
{
  int bid = blockIdx.x;
  if (bid < 2048) {
    int idx = bid * 256 + threadIdx.x;          // 32 pair-planes * HW
    int pp = idx >> 14;
    int hw = idx & (HWdim - 1);
    int y = hw >> 7, x = hw & 127;
    int z = pp >> 3, cp = pp & 7;
    const float* src = (z < 2) ? bg : tg;
    int b = z & 1;
    float av = src[((b * C_CH + 2 * cp) << 14) + hw];
    float bv = src[((b * C_CH + 2 * cp + 1) << 14) + hw];
    xpad2[(size_t)pp * XPL + (y + 6) * XWP + (x + 6)] = pack2(av, bv);
    return;
  }
  int p = bid - 2048;                           // 0..1175 = (196 x, 6 y)
  int gy = p / 196, gx = p - gy * 196;
  PrepDesc de = a.d[gy];
  int n = de.M * de.D;
  int idx = gx * 256 + threadIdx.x;
  if (idx >= n) return;
  int m = idx / de.D;
  int d = idx - m * de.D;
  float val = de.mem[idx];
  float sc = de.temp[0] / sqrtf((float)de.D);
  int pp = de.P * de.P;
  int c = d / pp;
  int r = d - c * pp;
  int i = r / de.P;
  int j = r - i * de.P;
  int uv = i * de.P + j;                 // unflipped (sim correlation)
  int uvp = uv >> 1, luv = uv & 1;
  int kk = luv * 16 + c, kg = kk >> 3, kl = kk & 7;
  int u = de.P - 1 - i, v = de.P - 1 - j;
  int uvf = u * de.P + v;                // flipped (read fold)
  float sv = val * sc;
  if (!de.tg) {
    int mt = m >> 4, row = m & 15;
    size_t bi = ((size_t)uvp * 4 + mt) * 512 + row * 32 +
                (size_t)((kg ^ (row & 3)) * 8 + kl);
    de.simA[bi] = (_Float16)sv;
    int ck = m >> 5, m5 = m & 31, kg2 = m5 >> 3, kl2 = m5 & 7;
    size_t b2 = (size_t)uvf * 1024 + (size_t)ck * 512 + c * 32 +
                (size_t)((kg2 ^ (c & 3)) * 8 + kl2);
    de.readA[b2] = (_Float16)val;
  } else {
    size_t bi = (size_t)uvp * 512 + m * 32 +
                (size_t)((kg ^ (m & 3)) * 8 + kl);
    de.simA[bi] = (_Float16)sv;          // m in 0..7, rows 8..15 stay zero
    int ch = uvf >> 2, q = uvf & 3;
    size_t b2 = (size_t)ch * 512 + c * 32 +
                (size_t)((q ^ (c & 3)) * 8 + (m & 7));
    de.readA[b2] = (_Float16)val;
  }
}

// ---------------------------------------------------------------------------
// Fully fused sim + softmax + read (+ pooled partial) for bg AND tg.
// Block = 16x16 out px, 512 thr. LDS 72704 B, 2 blocks/CU:
//   [0,25088)      x-halo [h][pix][16B]          (sim phase)
//   [25088,41472)  sim A double buffer 2x8KB     (2 uvp/chunk)
//   [0,63488)      att (bg 128B/px swz, tg 16B)  (read phase; aliases both)
//   [63488,71680)  read A double buffer 2x4KB
//   [71680,72704)  pooled scratch
// Sim: 1 barrier / 2-uvp chunk. Read: 1 barrier/chunk (dbuf, prefetch
// overlapped). Pad uv slots have zero-A (alloc zeroed); BOTH uva and uvb
// are clamped to P*P-1 so B addresses stay in the WRITTEN halo region
// (r10 bug: unclamped uva read stale LDS -> f16 NaN patterns -> 0*NaN).
// z: 0..5 bg (si*2+b), 6..11 tg. si 0..2 = {P7,P5,P3}.
// NOTE: (512,4) — do NOT raise min-waves (r6: spill); do NOT move A to
// global (r8: latency-bound).
// ---------------------------------------------------------------------------
struct FusedArgs {
  const unsigned* xpad2;
  const _Float16* simA[3];
  const _Float16* readA[3];
  const _Float16* simAtg[3];
  const _Float16* readAtg[3];
  float* fbgs[3];
  float* ftgs[3];
  float* pooled;
};

#define SDB_OFF 25088
#define RBUF_OFF 63488
#define PSCR_OFF 71680
#define FX_SMEM 72704

template<int P, bool BG>
__device__ __forceinline__ void fused_body(
    const unsigned* __restrict__ xp,          // + plane base
    const _Float16* __restrict__ simA,
    const _Float16* __restrict__ readA,
    float* __restrict__ fout,                 // + b*CHW
    float* __restrict__ poolp,                // pooled + branch/b base
    unsigned char* smem, int tid, int x0, int y0)
{
  constexpr int PAD = P / 2;
  constexpr int THY = 16 + 2 * PAD, THX = 16 + 2 * PAD;  // att halo
  constexpr int XH = 16 + 4 * PAD, XW = 16 + 4 * PAD;    // x halo
  constexpr int NXP = XH * XW, NHP = THY * THX;
  constexpr int NT = (NHP + 15) / 16;
  constexpr int NUVP = (P * P + 1) / 2;
  constexpr int NSCH = (NUVP + 1) / 2;       // sim chunks (2 uvp each)
  constexpr int NCH = BG ? (P * P + 1) / 2 : (P * P + 3) / 4;
  constexpr int NMT = BG ? 4 : 1;
  constexpr int SCHB = BG ? 4096 : 1024;     // sim A bytes per uvp (f16 only)
  constexpr int SCHB2 = 2 * SCHB;            // sim A chunk bytes (2 uvp)
  constexpr int RCHB = BG ? 4096 : 1024;     // read A chunk bytes
  constexpr int SST = SCHB2 / 32;            // sim staging threads (2 uint4)
  constexpr int RLD = RCHB / 16;             // read staging threads (1 uint4)
  constexpr int NRACC = BG ? 2 : 1;
  constexpr int NTI = 4;                     // sim N-tiles per wave

  unsigned char* xbuf = smem;                // sim phase
  unsigned char* att  = smem;                // read phase (aliases xbuf+sdb)
  unsigned char* sdb  = smem + SDB_OFF;      // sim A dbuf (2 x SCHB2)
  unsigned char* rdb  = smem + RBUF_OFF;     // read A dbuf (2 x RCHB)
  float* pscr = (float*)(smem + PSCR_OFF);

  const int w = __builtin_amdgcn_readfirstlane(tid >> 6);
  const int lane = tid & 63;
  const int col = lane & 15, g = lane >> 4;
  const int alo = col * 64 + ((g ^ (col & 3)) << 4);   // per-lane A frag off

  // ---- stage x halo as [h][pix][16B] (c = h*8..h*8+7), b128 writes ----
  const int oy = y0 - 2 * PAD + 6, ox = x0 - 2 * PAD + 6;
  for (int t = tid; t < 2 * NXP; t += 512) {
    int h = (t >= NXP) ? 1 : 0;
    int pix = t - h * NXP;
    int ly = pix / XW, lx = pix - ly * XW;
    const unsigned* s = xp + (size_t)(h * 4) * XPL + (oy + ly) * XWP + (ox + lx);
    uint4 vv = { s[0], s[XPL], s[2 * XPL], s[3 * XPL] };
    *(uint4*)(xbuf + (h * NXP + pix) * 16) = vv;
  }

  // ---- per-tile pixel coords (wave w: tiles w, w+8, w+16, w+24) ----
  int ayv[NTI], axv[NTI];
#pragma unroll
  for (int ti = 0; ti < NTI; ++ti) {
    int nt = w + ti * 8;
    int pix = nt * 16 + col;
    if (pix > NHP - 1) pix = NHP - 1;
    ayv[ti] = pix / THX;
    axv[ti] = pix - ayv[ti] * THX;
  }

  f32x4 acc[NTI][NMT];
#pragma unroll
  for (int ti = 0; ti < NTI; ++ti)
#pragma unroll
    for (int mt = 0; mt < NMT; ++mt) acc[ti][mt] = (f32x4){0.f, 0.f, 0.f, 0.f};

  // ---- sim K-loop: 2-uvp chunks, double-buffered A, 1 barrier/chunk ----
  uint4 s0, s1;
  if (tid < SST) {
    const uint4* p = (const uint4*)simA + tid * 2;
    s0 = p[0]; s1 = p[1];
  }
  for (int c = 0; c < NSCH; ++c) {
    if (tid < SST) {
      uint4* q = (uint4*)(sdb + (c & 1) * SCHB2) + tid * 2;
      q[0] = s0; q[1] = s1;
      if (c + 1 < NSCH) {
        const uint4* p = (const uint4*)(simA + (size_t)(c + 1) * (SCHB2 / 2)) + tid * 2;
        s0 = p[0]; s1 = p[1];
      }
    }
    __syncthreads();

#pragma unroll
    for (int l = 0; l < 2; ++l) {
      const int uvp = 2 * c + l;
      const unsigned char* ab = sdb + (c & 1) * SCHB2 + l * SCHB;
      f16x8 af[NMT];
#pragma unroll
      for (int mt = 0; mt < NMT; ++mt)
        af[mt] = *(const f16x8*)(ab + mt * 1024 + alo);

      // pad slots (uva/uvb >= P*P) have zero A; clamp BOTH so the B
      // address stays inside the written halo (r10 NaN fix).
      int uva = 2 * uvp;
      int uvb = uva + 1;
      if (uva >= P * P) uva = P * P - 1;
      if (uvb >= P * P) uvb = P * P - 1;
      const int ua = uva / P, va = uva - ua * P;
      const int ub = uvb / P, vb = uvb - ub * P;
      const int u_ = (g >= 2) ? ub : ua;
      const int v_ = (g >= 2) ? vb : va;

#pragma unroll
      for (int ti = 0; ti < NTI; ++ti) {
        int nt = w + ti * 8;
        if (nt < NT) {
          int xpix = (ayv[ti] + u_) * XW + axv[ti] + v_;
          f16x8 bb = *(const f16x8*)(xbuf + ((g & 1) * NXP + xpix) * 16);
#pragma unroll
          for (int mt = 0; mt < NMT; ++mt)
            acc[ti][mt] = __builtin_amdgcn_mfma_f32_16x16x32_f16(af[mt], bb, acc[ti][mt], 0, 0, 0);
        }
      }
    }
  }

  // prefetch first read-A chunk; fence xbuf/sdb reads before att overwrites
  uint4 rreg;
  if (tid < RLD) rreg = *((const uint4*)readA + tid);
  __syncthreads();

  // ---- softmax + att store to LDS (att aliases xbuf+sdb region) ----
#pragma unroll
  for (int ti = 0; ti < NTI; ++ti) {
    int nt = w + ti * 8;
    if (nt < NT) {
      int pa = nt * 16 + col;
      int say = pa / THX, sax = pa - say * THX;
      int gy = y0 + say - PAD, gx = x0 + sax - PAD;
      bool inimg = (pa < NHP) & (gy >= 0) & (gy < Hdim) & (gx >= 0) & (gx < Wdim);
      if constexpr (BG) {
        float l[16];
#pragma unroll
        for (int mt = 0; mt < 4; ++mt)
#pragma unroll
          for (int r = 0; r < 4; ++r) l[mt * 4 + r] = acc[ti][mt][r];
        float mx = l[0];
#pragma unroll
        for (int i2 = 1; i2 < 16; ++i2) mx = fmaxf(mx, l[i2]);
        mx = fmaxf(mx, __shfl_xor(mx, 16));
        mx = fmaxf(mx, __shfl_xor(mx, 32));
        float sum = 0.f;
#pragma unroll
        for (int i2 = 0; i2 < 16; ++i2) { l[i2] = __expf(l[i2] - mx); sum += l[i2]; }
        sum += __shfl_xor(sum, 16);
        sum += __shfl_xor(sum, 32);
        float inv = inimg ? (1.f / sum) : 0.f;
        unsigned char* base = att + pa * 128;
        int swz = (pa & 7) << 4;
#pragma unroll
        for (int mt = 0; mt < 4; ++mt) {
          uint2 st = { pack2(l[mt * 4 + 0] * inv, l[mt * 4 + 1] * inv),
                       pack2(l[mt * 4 + 2] * inv, l[mt * 4 + 3] * inv) };
          *(uint2*)(base + ((mt * 32 + g * 8) ^ swz)) = st;
        }
      } else {
        float l0 = acc[ti][0][0], l1 = acc[ti][0][1];
        float l2 = acc[ti][0][2], l3 = acc[ti][0][3];
        float mx = fmaxf(fmaxf(l0, l1), fmaxf(l2, l3));
        mx = fmaxf(mx, __shfl_xor(mx, 16));      // g0<->g1 (m 0..7)
        l0 = __expf(l0 - mx); l1 = __expf(l1 - mx);
        l2 = __expf(l2 - mx); l3 = __expf(l3 - mx);
        float sum = l0 + l1 + l2 + l3;
        sum += __shfl_xor(sum, 16);
        float inv = inimg ? (1.f / sum) : 0.f;
        if (g < 2) {                              // m = g*4 + r
          uint2 st = { pack2(l0 * inv, l1 * inv), pack2(l2 * inv, l3 * inv) };
          *(uint2*)(att + pa * 16 + g * 8) = st;
        }
      }
    }
  }

  // ---- read phase: wave w owns rows 2w, 2w+1; double-buffered A ----
  f32x4 racc[2][NRACC];
#pragma unroll
  for (int r = 0; r < 2; ++r)
#pragma unroll
    for (int q = 0; q < NRACC; ++q) racc[r][q] = (f32x4){0.f, 0.f, 0.f, 0.f};

  for (int ch = 0; ch < NCH; ++ch) {
    if (tid < RLD) {
      *((uint4*)(rdb + (ch & 1) * RCHB) + tid) = rreg;
      if (ch + 1 < NCH)
        rreg = *((const uint4*)(readA + (size_t)(ch + 1) * (RCHB / 2)) + tid);
    }
    __syncthreads();                 // staged visible; att ready at ch==0
    const unsigned char* ab = rdb + (ch & 1) * RCHB;
    if constexpr (BG) {
#pragma unroll
      for (int l = 0; l < 2; ++l) {
        int uv = 2 * ch + l;
        int uvc = (uv > P * P - 1) ? (P * P - 1) : uv;
        int u = uvc / P, v = uvc - u * P;
#pragma unroll
        for (int r = 0; r < 2; ++r) {
          int pix = (2 * w + r + u) * THX + (col + v);
          int swz = (pix & 7) << 4;
#pragma unroll
          for (int ck = 0; ck < 2; ++ck) {
            f16x8 bb = *(const f16x8*)(att + pix * 128 + ((ck * 64 + g * 16) ^ swz));
            f16x8 ah = *(const f16x8*)(ab + (l * 2 + ck) * 1024 + alo);
            racc[r][ck] = __builtin_amdgcn_mfma_f32_16x16x32_f16(ah, bb, racc[r][ck], 0, 0, 0);
          }
        }
      }
    } else {
      int uv = 4 * ch + g;                        // lane's g = K-slot q
      if (uv > P * P - 1) uv = P * P - 1;         // pad: zero A rows
      int u = uv / P, v = uv - u * P;
      f16x8 ah = *(const f16x8*)(ab + alo);
#pragma unroll
      for (int r = 0; r < 2; ++r) {
        int pix = (2 * w + r + u) * THX + (col + v);
        f16x8 bb = *(const f16x8*)(att + pix * 16);
        racc[r][0] = __builtin_amdgcn_mfma_f32_16x16x32_f16(ah, bb, racc[r][0], 0, 0, 0);
      }
    }
  }

  // ---- epilogue: divisor + store + pooled partial (shfl tree) ----
#pragma unroll
  for (int r = 0; r < 2; ++r) {
    f32x4 sv;
    if constexpr (BG) sv = racc[r][0] + racc[r][1];
    else              sv = racc[r][0];
    int gy = y0 + 2 * w + r, gx = x0 + col;
    int cy = min(P - 1, gy + PAD) - max(0, gy + PAD - (Hdim - 1)) + 1;
    int cx = min(P - 1, gx + PAD) - max(0, gx + PAD - (Wdim - 1)) + 1;
    float inv = 1.f / ((float)(cy * cx) + 1e-8f);
    float o0 = sv[0] * inv, o1 = sv[1] * inv, o2 = sv[2] * inv, o3 = sv[3] * inv;
    float* outp = fout + (size_t)(g * 4) * HWdim + gy * Wdim + gx;
    outp[0] = o0;
    outp[(size_t)1 * HWdim] = o1;
    outp[(size_t)2 * HWdim] = o2;
    outp[(size_t)3 * HWdim] = o3;

    float s0v = o0, s1v = o1, s2v = o2, s3v = o3;
#pragma unroll
    for (int mask = 1; mask < 16; mask <<= 1) {
      s0v += __shfl_xor(s0v, mask);
      s1v += __shfl_xor(s1v, mask);
      s2v += __shfl_xor(s2v, mask);
      s3v += __shfl_xor(s3v, mask);
    }
    if (col == 0) {
      float* rp = pscr + ((2 * w + r) * 4 + g) * 4;
      rp[0] = s0v; rp[1] = s1v; rp[2] = s2v; rp[3] = s3v;
    }
  }
  __syncthreads();                           // pool scratch ready
  if (tid < 16) {                            // c = tid = g*4+r
    float t = 0.f;
#pragma unroll
    for (int ww = 0; ww < 16; ++ww) t += pscr[ww * 16 + tid];
    gadd(poolp + tid, t * (1.0f / (float)HWdim));
  }
}

__global__ __launch_bounds__(512, 4) void k_fused(FusedArgs a) {
  __shared__ __align__(16) unsigned char smem[FX_SMEM];
  const int z = blockIdx.z;
  const int x0 = blockIdx.x * 16, y0 = blockIdx.y * 16;
  const int tid = threadIdx.x;
  if (z < 6) {
    const int si = z >> 1, b = z & 1;
    const unsigned* xp = a.xpad2 + (size_t)(b * 8) * XPL;
    float* pp = a.pooled + b * 16;
    if (si == 0)
      fused_body<7, true>(xp, a.simA[0], a.readA[0], a.fbgs[0] + (size_t)b * CHW, pp, smem, tid, x0, y0);
    else if (si == 1)
      fused_body<5, true>(xp, a.simA[1], a.readA[1], a.fbgs[1] + (size_t)b * CHW, pp, smem, tid, x0, y0);
    else
      fused_body<3, true>(xp, a.simA[2], a.readA[2], a.fbgs[2] + (size_t)b * CHW, pp, smem, tid, x0, y0);
  } else {
    const int zz = z - 6, si = zz >> 1, b = zz & 1;
    const unsigned* xp = a.xpad2 + (size_t)((2 + b) * 8) * XPL;
    float* pp = a.pooled + 32 + b * 16;
    if (si == 0)
      fused_body<7, false>(xp, a.simAtg[0], a.readAtg[0], a.ftgs[0] + (size_t)b * CHW, pp, smem, tid, x0, y0);
    else if (si == 1)
      fused_body<5, false>(xp, a.simAtg[1], a.readAtg[1], a.ftgs[1] + (size_t)b * CHW, pp, smem, tid, x0, y0);
    else
      fused_body<3, false>(xp, a.simAtg[2], a.readAtg[2], a.ftgs[2] + (size_t)b * CHW, pp, smem, tid, x0, y0);
  }
}

// ---------------------------------------------------------------------------
// Output blend with inlined fusion MLP (per-block recompute from pooled).
// 1024 blocks x 256 thr; each thread handles one float4 quad.
// ---------------------------------------------------------------------------
__global__ __launch_bounds__(256) void k_out(
    const float* __restrict__ fbg, const float* __restrict__ ftg,
    const float* __restrict__ pooled,
    const float* __restrict__ w1b, const float* __restrict__ b1b,
    const float* __restrict__ w2b, const float* __restrict__ b2b,
    const float* __restrict__ w1t, const float* __restrict__ b1t,
    const float* __restrict__ w2t, const float* __restrict__ b2t,
    float* __restrict__ out)
{
  __shared__ float hdn[2][2][4];
  __shared__ float lgs[2][2][48];
  __shared__ float swt[12][16];
  const int t = threadIdx.x;
  if (t < 16) {                 // br=t>>3, b=(t>>2)&1, h=t&3
    int br = t >> 3, b = (t >> 2) & 1, h = t & 3;
    const float* w1 = br ? w1t : w1b;
    const float* b1 = br ? b1t : b1b;
    float s = b1[h];
    for (int c = 0; c < C_CH; ++c) s += pooled[br * 32 + b * 16 + c] * w1[h * 16 + c];
    hdn[br][b][h] = fmaxf(s, 0.f);
  }
  __syncthreads();
  if (t < 192) {                // br=t/96, b, j
    int br = t / 96, r = t - br * 96, b = r / 48, j = r - b * 48;
    const float* w2 = br ? w2t : w2b;
    const float* b2 = br ? b2t : b2b;
    float s = b2[j];
    for (int h = 0; h < 4; ++h) s += hdn[br][b][h] * w2[j * 4 + h];
    lgs[br][b][j] = s;
  }
  __syncthreads();
  if (t < 64) {                 // br=t>>5, b=(t>>4)&1, c=t&15
    int br = t >> 5, b = (t >> 4) & 1, c = t & 15;
    float l0 = lgs[br][b][c], l1 = lgs[br][b][16 + c], l2 = lgs[br][b][32 + c];
    float m = fmaxf(l0, fmaxf(l1, l2));
    float e0 = __expf(l0 - m), e1 = __expf(l1 - m), e2 = __expf(l2 - m);
    float inv = 1.f / (e0 + e1 + e2);
    swt[(br * 2 + b) * 3 + 0][c] = e0 * inv;
    swt[(br * 2 + b) * 3 + 1][c] = e1 * inv;
    swt[(br * 2 + b) * 3 + 2][c] = e2 * inv;
  }
  __syncthreads();

  int base = (blockIdx.x * 256 + t) * 4;         // quad base, 0..2^20
  int br  = base >> 19;
  int rem = base & ((1 << 19) - 1);
  int b   = rem >> 18;
  int off = rem & ((1 << 18) - 1);
  int c   = off >> 14;
  const float* f = (br == 0) ? fbg : ftg;
  int wb = (br * 2 + b) * 3;
  f32x4 acc = {0.f, 0.f, 0.f, 0.f};
#pragma unroll
  for (int s = 0; s < 3; ++s) {
    f32x4 v = *(const f32x4*)(f + (size_t)(s * 2 + b) * CHW + off);
    float wv = swt[wb + s][c];
    acc = __builtin_elementwise_fma((f32x4){wv, wv, wv, wv}, v, acc);
  }
  *(f32x4*)(out + base) = acc;
}

// ---------------------------------------------------------------------------
extern "C" void kernel_launch(void* const* d_in, const int* in_sizes, int n_in,
                              void* d_out, int out_size, void* d_ws, size_t ws_size,
                              hipStream_t stream)
{
  const float* bg = (const float*)d_in[0];
  const float* tg = (const float*)d_in[1];
  const float* bg_mem[3]  = {(const float*)d_in[2],  (const float*)d_in[6],  (const float*)d_in[10]};
  const float* tg_mem[3]  = {(const float*)d_in[3],  (const float*)d_in[7],  (const float*)d_in[11]};
  const float* bg_temp[3] = {(const float*)d_in[4],  (const float*)d_in[8],  (const float*)d_in[12]};
  const float* tg_temp[3] = {(const float*)d_in[5],  (const float*)d_in[9],  (const float*)d_in[13]};
  const float* bg_fc1_w = (const float*)d_in[14];
  const float* bg_fc1_b = (const float*)d_in[15];
  const float* bg_fc2_w = (const float*)d_in[16];
  const float* bg_fc2_b = (const float*)d_in[17];
  const float* tg_fc1_w = (const float*)d_in[18];
  const float* tg_fc1_b = (const float*)d_in[19];
  const float* tg_fc2_w = (const float*)d_in[20];
  const float* tg_fc2_b = (const float*)d_in[21];

  unsigned* ws = (unsigned*)d_ws;
  unsigned* xpad2   = ws;                                    // 627,200 u32
  float*    pooled  = (float*)(ws + (size_t)32 * XPL);       // 64
  float*    wt      = pooled + 64;                           // 192 (pad)
  _Float16* simA    = (_Float16*)(wt + 192);                 // 94,208 halfs
  _Float16* readA   = simA + 94208;                          // 88,064 halfs
  _Float16* simAtg  = readA + 88064;                         // 23,552 halfs
  _Float16* readAtg = simAtg + 23552;                        // 11,776 halfs
  float*    ftg     = (float*)(readAtg + 11776);             // 6*CHW
  float*    fbg     = ftg + (size_t)6 * CHW;                 // 6*CHW

  // zero xpad2 border + pooled + all A arrays (incl. pad slots):
  // 627200 + 64 + 192 + 47104 + 44032 + 11776 + 5888 = 736256 u32
  hipMemsetAsync(xpad2, 0, (size_t)736256 * 4, stream);

  const int   Ms[6] = {64, 64, 64, 8, 8, 8};
  const int   Ps[6] = {3, 5, 7, 3, 5, 7};
  const float* mems[6]  = {bg_mem[0], bg_mem[1], bg_mem[2], tg_mem[0], tg_mem[1], tg_mem[2]};
  const float* temps[6] = {bg_temp[0], bg_temp[1], bg_temp[2], tg_temp[0], tg_temp[1], tg_temp[2]};

  // per-scale offsets (halfs), si 0..2 = P7,P5,P3
  const size_t aOffS[3]  = {0, 53248, 81920};     // bg sim (NUVP+1 uvp each)
  const size_t aOffR[3]  = {0, 51200, 77824};     // bg read (P*P+1 uv slots)
  const size_t sOffTg[3] = {0, 13312, 20480};     // tg sim (NUVP+1 uvp each)
  const size_t rOffTg[3] = {0, 6656, 10240};      // tg read (NCH chunks)

  PrepArgs pa;
  for (int k = 0; k < 6; ++k) {
    int D = C_CH * Ps[k] * Ps[k];
    int si = 2 - (k % 3);                         // PS index -> scale index
    if (k < 3)
      pa.d[k] = {mems[k], temps[k], simA + aOffS[si], readA + aOffR[si],
                 Ms[k], D, Ps[k], 0};
    else
      pa.d[k] = {mems[k], temps[k], simAtg + sOffTg[si], readAtg + rOffTg[si],
                 Ms[k], D, Ps[k], 1};
  }
  k_preppad<<<3224, 256, 0, stream>>>(pa, bg, tg, xpad2);

  FusedArgs fa;
  fa.xpad2 = xpad2;
  fa.pooled = pooled;
  for (int si = 0; si < 3; ++si) {
    int p = 2 - si;
    fa.simA[si]    = simA + aOffS[si];
    fa.readA[si]   = readA + aOffR[si];
    fa.simAtg[si]  = simAtg + sOffTg[si];
    fa.readAtg[si] = readAtg + rOffTg[si];
    fa.fbgs[si]    = fbg + (size_t)p * 2 * CHW;
    fa.ftgs[si]    = ftg + (size_t)p * 2 * CHW;
  }

  k_fused<<<dim3(8, 8, 12), 512, 0, stream>>>(fa);

  k_out<<<1024, 256, 0, stream>>>(fbg, ftg, pooled,
                                  bg_fc1_w, bg_fc1_b, bg_fc2_w, bg_fc2_b,
                                  tg_fc1_w, tg_fc1_b, tg_fc2_w, tg_fc2_b,
                                  (float*)d_out);
}